// Round 1
// baseline (6643.942 us; speedup 1.0000x reference)
//
#include <hip/hip_runtime.h>

// Problem constants (AttentionMultipleHead: B=4,S=2048,D=512,H=8,INNER=512)
#define BM 128
#define BN 128
#define BKT 16

// Generic fp32 tiled GEMM: C[z] = alpha * A[z] @ op(B[z]) (+ bias) (+ C)
// A: [M,K] row-major (lda). TB=false: B [K,N] row-major (ldb). TB=true: B [N,K] row-major (ldb).
// Dims must be multiples of tile sizes (they are: M=2048, N in {512,2048}, K in {512,2048}).
template <bool TB, bool ACC, bool BIAS>
__global__ __launch_bounds__(256) void gemm_kernel(
    const float* __restrict__ A, int lda, long long sAz,
    const float* __restrict__ Bp, int ldb, long long sBz,
    const float* __restrict__ bias,
    float* __restrict__ C, int ldc, long long sCz,
    int K, float alpha) {
  __shared__ float As[BKT][BM];
  __shared__ float Bs[BKT][BN];
  const int t = threadIdx.x;
  const int tx = t & 15, ty = t >> 4;
  const long long row0 = (long long)blockIdx.y * BM;
  const long long col0 = (long long)blockIdx.x * BN;
  A += (long long)blockIdx.z * sAz + row0 * lda;
  Bp += (long long)blockIdx.z * sBz;
  C += (long long)blockIdx.z * sCz;

  // A-tile loader: two float4s per thread along K, rows ar0 / ar1.
  const int ar0 = t >> 2;          // 0..63
  const int ar1 = ar0 + 64;        // 64..127
  const int ak = (t & 3) << 2;     // 0,4,8,12
  // B-tile loader (non-transposed): two float4s along N.
  const int bkr = t >> 5;          // 0..7
  const int bn = (t & 31) << 2;    // 0..124

  float acc[8][8];
#pragma unroll
  for (int i = 0; i < 8; ++i)
#pragma unroll
    for (int j = 0; j < 8; ++j) acc[i][j] = 0.f;

  for (int k0 = 0; k0 < K; k0 += BKT) {
    const float4 a0 = *(const float4*)(A + (long long)ar0 * lda + (k0 + ak));
    const float4 a1 = *(const float4*)(A + (long long)ar1 * lda + (k0 + ak));
    float4 b0, b1;
    if (TB) {
      b0 = *(const float4*)(Bp + (col0 + ar0) * (long long)ldb + (k0 + ak));
      b1 = *(const float4*)(Bp + (col0 + ar1) * (long long)ldb + (k0 + ak));
    } else {
      b0 = *(const float4*)(Bp + (long long)(k0 + bkr) * ldb + col0 + bn);
      b1 = *(const float4*)(Bp + (long long)(k0 + bkr + 8) * ldb + col0 + bn);
    }
    __syncthreads();  // previous iteration's LDS reads complete
    As[ak + 0][ar0] = a0.x; As[ak + 1][ar0] = a0.y;
    As[ak + 2][ar0] = a0.z; As[ak + 3][ar0] = a0.w;
    As[ak + 0][ar1] = a1.x; As[ak + 1][ar1] = a1.y;
    As[ak + 2][ar1] = a1.z; As[ak + 3][ar1] = a1.w;
    if (TB) {
      Bs[ak + 0][ar0] = b0.x; Bs[ak + 1][ar0] = b0.y;
      Bs[ak + 2][ar0] = b0.z; Bs[ak + 3][ar0] = b0.w;
      Bs[ak + 0][ar1] = b1.x; Bs[ak + 1][ar1] = b1.y;
      Bs[ak + 2][ar1] = b1.z; Bs[ak + 3][ar1] = b1.w;
    } else {
      *(float4*)&Bs[bkr][bn] = b0;
      *(float4*)&Bs[bkr + 8][bn] = b1;
    }
    __syncthreads();
#pragma unroll
    for (int kk = 0; kk < BKT; ++kk) {
      float av[8], bv[8];
      *(float4*)&av[0] = *(const float4*)&As[kk][ty << 2];
      *(float4*)&av[4] = *(const float4*)&As[kk][64 + (ty << 2)];
      *(float4*)&bv[0] = *(const float4*)&Bs[kk][tx << 2];
      *(float4*)&bv[4] = *(const float4*)&Bs[kk][64 + (tx << 2)];
#pragma unroll
      for (int i = 0; i < 8; ++i)
#pragma unroll
        for (int j = 0; j < 8; ++j) acc[i][j] = fmaf(av[i], bv[j], acc[i][j]);
    }
  }

#pragma unroll
  for (int i = 0; i < 8; ++i) {
    const long long r = row0 + ((i < 4) ? (ty * 4 + i) : (64 + ty * 4 + (i - 4)));
    float* crow = C + r * ldc + col0;
#pragma unroll
    for (int jh = 0; jh < 2; ++jh) {
      const int cl = jh * 64 + (tx << 2);
      float4 v;
      v.x = acc[i][jh * 4 + 0] * alpha;
      v.y = acc[i][jh * 4 + 1] * alpha;
      v.z = acc[i][jh * 4 + 2] * alpha;
      v.w = acc[i][jh * 4 + 3] * alpha;
      if (BIAS) {
        const float* bp_ = bias + col0 + cl;
        v.x += bp_[0]; v.y += bp_[1]; v.z += bp_[2]; v.w += bp_[3];
      }
      if (ACC) {
        const float4 o = *(const float4*)(crow + cl);
        v.x += o.x; v.y += o.y; v.z += o.z; v.w += o.w;
      }
      *(float4*)(crow + cl) = v;
    }
  }
}

// Row softmax over S=2048 columns; one block (256 threads) per row.
__global__ __launch_bounds__(256) void softmax_kernel(float* __restrict__ sc) {
  const int S = 2048;
  const int t = threadIdx.x;
  float* p = sc + ((long long)blockIdx.y * S + blockIdx.x) * S;
  float vals[8];
  float m = -1e30f;
#pragma unroll
  for (int u = 0; u < 8; ++u) {
    vals[u] = p[t + 256 * u];
    m = fmaxf(m, vals[u]);
  }
#pragma unroll
  for (int off = 32; off; off >>= 1) m = fmaxf(m, __shfl_xor(m, off, 64));
  __shared__ float redm[4];
  __shared__ float reds[4];
  if ((t & 63) == 0) redm[t >> 6] = m;
  __syncthreads();
  m = fmaxf(fmaxf(redm[0], redm[1]), fmaxf(redm[2], redm[3]));
  float s = 0.f;
#pragma unroll
  for (int u = 0; u < 8; ++u) {
    vals[u] = __expf(vals[u] - m);
    s += vals[u];
  }
#pragma unroll
  for (int off = 32; off; off >>= 1) s += __shfl_xor(s, off, 64);
  if ((t & 63) == 0) reds[t >> 6] = s;
  __syncthreads();
  s = reds[0] + reds[1] + reds[2] + reds[3];
  const float inv = 1.f / s;
#pragma unroll
  for (int u = 0; u < 8; ++u) p[t + 256 * u] = vals[u] * inv;
}

// out[b,s,:] = bp[:] (projection GEMMs then accumulate per head)
__global__ __launch_bounds__(256) void init_out_kernel(float* __restrict__ out,
                                                       const float* __restrict__ bp,
                                                       int total) {
  const int i = blockIdx.x * 256 + threadIdx.x;
  if (i < total) out[i] = bp[i & 511];  // D=512
}

extern "C" void kernel_launch(void* const* d_in, const int* in_sizes, int n_in,
                              void* d_out, int out_size, void* d_ws, size_t ws_size,
                              hipStream_t stream) {
  constexpr int Bb = 4, S = 2048, D = 512, H = 8, E = 512;
  const float* x  = (const float*)d_in[0];
  const float* Wq = (const float*)d_in[1];
  const float* bq = (const float*)d_in[2];
  const float* Wk = (const float*)d_in[3];
  const float* bk = (const float*)d_in[4];
  const float* Wv = (const float*)d_in[5];
  const float* bv = (const float*)d_in[6];
  const float* Wp = (const float*)d_in[7];
  const float* bp = (const float*)d_in[8];
  float* out = (float*)d_out;

  // Workspace layout (fp32 elems): q,k,v,o each B*S*E = 4.19M; scores B*S*S = 16.78M.
  // Total 33.55M floats = 134.2 MB.
  const long long SLICE = (long long)Bb * S * E;
  float* q = (float*)d_ws;
  float* kb = q + SLICE;
  float* v = kb + SLICE;
  float* o = v + SLICE;
  float* sc = o + SLICE;

  const dim3 blk(256);
  {
    const int total = Bb * S * D;
    init_out_kernel<<<dim3((total + 255) / 256), blk, 0, stream>>>(out, bp, total);
  }
  const float scale = 0.044194173824159216f;  // 1/sqrt(512)

  const dim3 gP(E / BN, S / BM, Bb);  // 4 x 16 x 4  (2048x512 outputs)
  const dim3 gS(S / BN, S / BM, Bb);  // 16 x 16 x 4 (2048x2048 scores)

  for (int h = 0; h < H; ++h) {
    const long long wOff = (long long)h * D * E;
    // Q/K/V projections: [S,D] @ [D,E] + bias, per b (z)
    gemm_kernel<false, false, true><<<gP, blk, 0, stream>>>(
        x, D, (long long)S * D, Wq + wOff, E, 0, bq + h * E,
        q, E, (long long)S * E, D, 1.f);
    gemm_kernel<false, false, true><<<gP, blk, 0, stream>>>(
        x, D, (long long)S * D, Wk + wOff, E, 0, bk + h * E,
        kb, E, (long long)S * E, D, 1.f);
    gemm_kernel<false, false, true><<<gP, blk, 0, stream>>>(
        x, D, (long long)S * D, Wv + wOff, E, 0, bv + h * E,
        v, E, (long long)S * E, D, 1.f);
    // scores = (Q @ K^T) / sqrt(E)
    gemm_kernel<true, false, false><<<gS, blk, 0, stream>>>(
        q, E, (long long)S * E, kb, E, (long long)S * E, nullptr,
        sc, S, (long long)S * S, E, scale);
    // row softmax
    softmax_kernel<<<dim3(S, Bb), blk, 0, stream>>>(sc);
    // O = P @ V
    gemm_kernel<false, false, false><<<gP, blk, 0, stream>>>(
        sc, S, (long long)S * S, v, E, (long long)S * E, nullptr,
        o, E, (long long)S * E, S, 1.f);
    // out += O @ Wp[h*E:(h+1)*E, :]
    gemm_kernel<false, true, false><<<gP, blk, 0, stream>>>(
        o, E, (long long)S * E, Wp + (long long)h * E * D, D, 0, nullptr,
        out, D, (long long)S * D, E, 1.f);
  }
}

// Round 2
// 1621.588 us; speedup vs baseline: 4.0972x; 4.0972x over previous
//
#include <hip/hip_runtime.h>

// R2: bf16 MFMA rewrite. B=4,S=2048,D=512,H=8,E=512. All GEMMs in NT form
// (A[M,K] bf16, B[N,K] bf16) via v_mfma_f32_16x16x32_bf16, fp32 accumulate.
// Fragment-linear LDS (lane's 16B frag at chunk*16) -> quad-contiguous
// ds_read_b128 / ds_write_b128. Single-barrier double-buffered K-loop.

typedef short s8v __attribute__((ext_vector_type(8)));      // 8 bf16 = 4 VGPRs
typedef float f4v __attribute__((ext_vector_type(4)));      // MFMA acc
typedef unsigned short us;
typedef us us4v __attribute__((ext_vector_type(4)));

__device__ inline us f2b(float f) {  // fp32 -> bf16 RNE
  union { float f; unsigned u; } v; v.f = f;
  unsigned r = v.u + 0x7FFFu + ((v.u >> 16) & 1u);
  return (us)(r >> 16);
}

// EPI: 0 = fp32*alpha out (scores); 1 = bf16 out (+bias); 2 = bf16 transposed
// out (V^T, ldc = lead dim of C^T) (+bias); 4 = fp32 accumulate (out-proj).
template <int EPI>
__global__ __launch_bounds__(256) void gemm_nt(
    const us* __restrict__ A, int lda, long long sAz,
    const us* __restrict__ Bm, int ldb, long long sBz,
    const float* __restrict__ bias,
    void* __restrict__ Cv, int ldc, long long sCz,
    int K, float alpha) {
  __shared__ us As[2][4096];  // 128 x 32 bf16, fragment-linear (512 chunks x 16B)
  __shared__ us Bs[2][4096];
  const int t = threadIdx.x;
  const int wv = t >> 6;
  const int ln = t & 63;
  const int m16 = ln & 15, quad = ln >> 4;
  const long long row0 = (long long)blockIdx.y * 128;
  const long long col0 = (long long)blockIdx.x * 128;
  const us* Az = A + blockIdx.z * sAz;
  const us* Bz = Bm + blockIdx.z * sBz;

  // Staging: thread t owns chunks t and t+256 of each tile.
  // chunk c = mb*64 + q*16 + m  ->  global row (row0+mb*16+m), k-cols q*8..q*8+7
  const int c1 = t, c2 = t + 256;
  const us* gA1 = Az + (row0 + (c1 >> 6) * 16 + (c1 & 15)) * (long long)lda + ((c1 >> 4) & 3) * 8;
  const us* gA2 = Az + (row0 + (c2 >> 6) * 16 + (c2 & 15)) * (long long)lda + ((c2 >> 4) & 3) * 8;
  const us* gB1 = Bz + (col0 + (c1 >> 6) * 16 + (c1 & 15)) * (long long)ldb + ((c1 >> 4) & 3) * 8;
  const us* gB2 = Bz + (col0 + (c2 >> 6) * 16 + (c2 & 15)) * (long long)ldb + ((c2 >> 4) & 3) * 8;

  f4v acc[4][4];
#pragma unroll
  for (int r = 0; r < 4; ++r)
#pragma unroll
    for (int c = 0; c < 4; ++c) acc[r][c] = (f4v){0.f, 0.f, 0.f, 0.f};

  // prologue: stage k0=0 into buffer 0
  s8v la1 = *(const s8v*)gA1, la2 = *(const s8v*)gA2;
  s8v lb1 = *(const s8v*)gB1, lb2 = *(const s8v*)gB2;
  gA1 += 32; gA2 += 32; gB1 += 32; gB2 += 32;
  *(s8v*)&As[0][c1 * 8] = la1; *(s8v*)&As[0][c2 * 8] = la2;
  *(s8v*)&Bs[0][c1 * 8] = lb1; *(s8v*)&Bs[0][c2 * 8] = lb2;

  const int nk = K >> 5;
  const int abase = (wv & 1) * 256;   // wave's m-block group (chunks)
  const int bbase = (wv >> 1) * 256;  // wave's n-block group
  const int fo = quad * 16 + m16;     // lane's chunk within a 16-row group

  for (int i = 0; i < nk; ++i) {
    __syncthreads();  // buf (i&1) writes visible; reads of buf ((i+1)&1) drained
    const int cur = i & 1;
    const bool more = (i + 1 < nk);
    if (more) {  // issue next tile's global loads early (latency overlaps MFMA)
      la1 = *(const s8v*)gA1; la2 = *(const s8v*)gA2;
      lb1 = *(const s8v*)gB1; lb2 = *(const s8v*)gB2;
      gA1 += 32; gA2 += 32; gB1 += 32; gB2 += 32;
    }
    s8v af[4], bf[4];
#pragma unroll
    for (int r = 0; r < 4; ++r) af[r] = *(const s8v*)&As[cur][(abase + r * 64 + fo) * 8];
#pragma unroll
    for (int c = 0; c < 4; ++c) bf[c] = *(const s8v*)&Bs[cur][(bbase + c * 64 + fo) * 8];
#pragma unroll
    for (int r = 0; r < 4; ++r)
#pragma unroll
      for (int c = 0; c < 4; ++c)
        acc[r][c] = __builtin_amdgcn_mfma_f32_16x16x32_bf16(af[r], bf[c], acc[r][c], 0, 0, 0);
    if (more) {
      const int nb = cur ^ 1;
      *(s8v*)&As[nb][c1 * 8] = la1; *(s8v*)&As[nb][c2 * 8] = la2;
      *(s8v*)&Bs[nb][c1 * 8] = lb1; *(s8v*)&Bs[nb][c2 * 8] = lb2;
    }
  }

  // Epilogue. C/D layout (m89-verified): col = lane&15, row = quad*4 + reg.
  const long long zz = blockIdx.z;
#pragma unroll
  for (int r = 0; r < 4; ++r) {
    const long long gr0 = row0 + (wv & 1) * 64 + r * 16 + quad * 4;
#pragma unroll
    for (int c = 0; c < 4; ++c) {
      const long long gc = col0 + (wv >> 1) * 64 + c * 16 + m16;
      if (EPI == 0) {
        float* C = (float*)Cv + zz * sCz;
        float* p = C + gr0 * ldc + gc;
#pragma unroll
        for (int g = 0; g < 4; ++g) p[(long long)g * ldc] = acc[r][c][g] * alpha;
      } else if (EPI == 1) {
        us* C = (us*)Cv + zz * sCz;
        const float bb = bias ? bias[gc] : 0.f;
#pragma unroll
        for (int g = 0; g < 4; ++g) C[(gr0 + g) * (long long)ldc + gc] = f2b(acc[r][c][g] + bb);
      } else if (EPI == 2) {
        us* C = (us*)Cv + zz * sCz;
        const float bb = bias ? bias[gc] : 0.f;
        us4v pk;
#pragma unroll
        for (int g = 0; g < 4; ++g) pk[g] = f2b(acc[r][c][g] + bb);
        *(us4v*)&C[gc * (long long)ldc + gr0] = pk;  // 8B store, gr0 % 4 == 0
      } else {  // EPI 4
        float* C = (float*)Cv + zz * sCz;
        float* p = C + gr0 * ldc + gc;
#pragma unroll
        for (int g = 0; g < 4; ++g) p[(long long)g * ldc] += acc[r][c][g];
      }
    }
  }
}

// Row softmax over 2048 cols, fp32 in -> bf16 out. One block per row.
__global__ __launch_bounds__(256) void softmax_kernel(const float* __restrict__ sc,
                                                      us* __restrict__ P) {
  const int t = threadIdx.x;
  const long long base = ((long long)blockIdx.y * 2048 + blockIdx.x) * 2048;
  const float* p = sc + base;
  us* po = P + base;
  float vals[8];
  float m = -1e30f;
#pragma unroll
  for (int u = 0; u < 8; ++u) {
    vals[u] = p[t + 256 * u];
    m = fmaxf(m, vals[u]);
  }
#pragma unroll
  for (int off = 32; off; off >>= 1) m = fmaxf(m, __shfl_xor(m, off, 64));
  __shared__ float redm[4];
  __shared__ float reds[4];
  if ((t & 63) == 0) redm[t >> 6] = m;
  __syncthreads();
  m = fmaxf(fmaxf(redm[0], redm[1]), fmaxf(redm[2], redm[3]));
  float s = 0.f;
#pragma unroll
  for (int u = 0; u < 8; ++u) {
    vals[u] = __expf(vals[u] - m);
    s += vals[u];
  }
#pragma unroll
  for (int off = 32; off; off >>= 1) s += __shfl_xor(s, off, 64);
  if ((t & 63) == 0) reds[t >> 6] = s;
  __syncthreads();
  s = reds[0] + reds[1] + reds[2] + reds[3];
  const float inv = 1.f / s;
#pragma unroll
  for (int u = 0; u < 8; ++u) po[t + 256 * u] = f2b(vals[u] * inv);
}

__global__ __launch_bounds__(256) void conv_bf16(const float* __restrict__ in,
                                                 us* __restrict__ out, int n4) {
  const int i = blockIdx.x * 256 + threadIdx.x;
  if (i < n4) {
    const float4 f = ((const float4*)in)[i];
    us4v o;
    o[0] = f2b(f.x); o[1] = f2b(f.y); o[2] = f2b(f.z); o[3] = f2b(f.w);
    ((us4v*)out)[i] = o;
  }
}

// in [Z][R][C] fp32 -> out [Z][C][R] bf16 (32x32 LDS tiles)
__global__ __launch_bounds__(256) void conv_transpose(const float* __restrict__ in,
                                                      us* __restrict__ out,
                                                      int R, int C) {
  __shared__ float tile[32][33];
  const int tx = threadIdx.x & 31, ty = threadIdx.x >> 5;
  const long long zo = (long long)blockIdx.z * R * C;
  const int r0 = blockIdx.y * 32, c0 = blockIdx.x * 32;
#pragma unroll
  for (int j = 0; j < 4; ++j)
    tile[ty + 8 * j][tx] = in[zo + (long long)(r0 + ty + 8 * j) * C + c0 + tx];
  __syncthreads();
#pragma unroll
  for (int j = 0; j < 4; ++j)
    out[zo + (long long)(c0 + ty + 8 * j) * R + r0 + tx] = f2b(tile[tx][ty + 8 * j]);
}

__global__ __launch_bounds__(256) void init_out_kernel(float* __restrict__ out,
                                                       const float* __restrict__ bp,
                                                       int total) {
  const int i = blockIdx.x * 256 + threadIdx.x;
  if (i < total) out[i] = bp[i & 511];  // D=512
}

extern "C" void kernel_launch(void* const* d_in, const int* in_sizes, int n_in,
                              void* d_out, int out_size, void* d_ws, size_t ws_size,
                              hipStream_t stream) {
  constexpr int Bb = 4, S = 2048, D = 512, H = 8, E = 512, HE = 4096;
  const float* x  = (const float*)d_in[0];
  const float* Wq = (const float*)d_in[1];
  const float* bq = (const float*)d_in[2];
  const float* Wk = (const float*)d_in[3];
  const float* bk = (const float*)d_in[4];
  const float* Wv = (const float*)d_in[5];
  const float* bv = (const float*)d_in[6];
  const float* Wp = (const float*)d_in[7];
  const float* bp = (const float*)d_in[8];
  float* out = (float*)d_out;

  // Workspace (~160 MB): all bf16 planes + fp32 scores.
  us* xh  = (us*)d_ws;          // [B][S][D]      4,194,304
  us* WqT = xh + 4194304;       // [H][E][D]      2,097,152
  us* WkT = WqT + 2097152;
  us* WvT = WkT + 2097152;
  us* WpT = WvT + 2097152;      // [D][HE]        2,097,152
  us* qh  = WpT + 2097152;      // per-h [B][S][E] 4,194,304
  us* kh  = qh + 4194304;
  us* vT  = kh + 4194304;       // per-h [B][E][S]
  us* oh  = vT + 4194304;       // per-h [B][S][E]
  us* P   = oh + 4194304;       // per-h [B][S][S] 16,777,216
  float* sc = (float*)(P + 16777216);  // per-h [B][S][S] fp32

  const dim3 tb(256);
  init_out_kernel<<<dim3((Bb * S * D + 255) / 256), tb, 0, stream>>>(out, bp, Bb * S * D);
  conv_bf16<<<dim3(4194304 / 4 / 256), tb, 0, stream>>>(x, xh, 4194304 / 4);
  conv_transpose<<<dim3(E / 32, D / 32, H), tb, 0, stream>>>(Wq, WqT, D, E);
  conv_transpose<<<dim3(E / 32, D / 32, H), tb, 0, stream>>>(Wk, WkT, D, E);
  conv_transpose<<<dim3(E / 32, D / 32, H), tb, 0, stream>>>(Wv, WvT, D, E);
  conv_transpose<<<dim3(D / 32, HE / 32, 1), tb, 0, stream>>>(Wp, WpT, HE, D);

  const float aS = 0.044194173824159216f;  // 1/sqrt(512)
  const dim3 gP(4, 16, 4), gS(16, 16, 4);
  for (int h = 0; h < H; ++h) {
    gemm_nt<1><<<gP, tb, 0, stream>>>(xh, D, (long long)S * D, WqT + h * E * D, D, 0,
                                      bq + h * E, qh, E, (long long)S * E, D, 1.f);
    gemm_nt<1><<<gP, tb, 0, stream>>>(xh, D, (long long)S * D, WkT + h * E * D, D, 0,
                                      bk + h * E, kh, E, (long long)S * E, D, 1.f);
    gemm_nt<2><<<gP, tb, 0, stream>>>(xh, D, (long long)S * D, WvT + h * E * D, D, 0,
                                      bv + h * E, vT, S, (long long)E * S, D, 1.f);
    gemm_nt<0><<<gS, tb, 0, stream>>>(qh, E, (long long)S * E, kh, E, (long long)S * E,
                                      nullptr, sc, S, (long long)S * S, E, aS);
    softmax_kernel<<<dim3(S, Bb), tb, 0, stream>>>(sc, P);
    gemm_nt<1><<<gP, tb, 0, stream>>>(P, S, (long long)S * S, vT, S, (long long)E * S,
                                      nullptr, oh, E, (long long)S * E, S, 1.f);
    gemm_nt<4><<<gP, tb, 0, stream>>>(oh, E, (long long)S * E, WpT + h * E, HE, 0,
                                      nullptr, out, D, (long long)S * D, E, 1.f);
  }
}

// Round 4
// 1203.346 us; speedup vs baseline: 5.5212x; 1.3476x over previous
//
#include <hip/hip_runtime.h>

// R4: R3 with the V^T-output stride bug fixed (sC1 was E*S*D instead of E*S).
// Structure: m97-style GEMM — global_load_lds(16B) staging, BK=64 single-buffer
// (32 MFMA/wave per barrier), heads batched into blockIdx.z (chunk size HC
// chosen from ws_size). Scores kept in bf16; softmax in-place bf16.

typedef short s8v __attribute__((ext_vector_type(8)));   // 8 bf16 = 4 VGPRs
typedef float f4v __attribute__((ext_vector_type(4)));
typedef unsigned short us;
typedef us us4v __attribute__((ext_vector_type(4)));
typedef us us8v __attribute__((ext_vector_type(8)));

__device__ inline us f2b(float f) {  // fp32 -> bf16 RNE
  union { float f; unsigned u; } v; v.f = f;
  unsigned r = v.u + 0x7FFFu + ((v.u >> 16) & 1u);
  return (us)(r >> 16);
}
__device__ inline float b2f(us b) {
  union { unsigned u; float f; } v; v.u = ((unsigned)b) << 16;
  return v.f;
}

// async global->LDS, 16 B per lane; LDS dest = wave-uniform base + lane*16.
__device__ inline void gld16(const us* g, us* l) {
  __builtin_amdgcn_global_load_lds(
      (const __attribute__((address_space(1))) void*)g,
      (__attribute__((address_space(3))) void*)l, 16, 0, 0);
}

// NT GEMM: C = alpha * A @ B^T (+bias) with A[M,K] (lda), B[N,K] (ldb), bf16.
// z-slicing: zo = z>>L picks stride0, zi = z&(2^L-1) picks stride1 (offsets
// = zo*s?0 + zi*s?1) so one launch covers (batch x head-chunk).
// EPI: 1 = bf16 out (+bias, *alpha); 2 = bf16 transposed out (V^T);
//      4 = fp32 accumulate out.
template <int EPI>
__global__ __launch_bounds__(256, 4) void gemm_nt(
    const us* __restrict__ A, int lda, long long sA0, long long sA1,
    const us* __restrict__ Bm, int ldb, long long sB0, long long sB1,
    const float* __restrict__ bias, long long sbias,
    void* __restrict__ Cv, int ldc, long long sC0, long long sC1,
    int K, float alpha, int L) {
  __shared__ us As[8192];  // 128 rows x 64 k, fragment-linear: 1024 chunks x 16B
  __shared__ us Bs[8192];
  const int t = threadIdx.x;
  const int wv = t >> 6, ln = t & 63;
  const int m16 = ln & 15, quad = ln >> 4;
  const long long row0 = (long long)blockIdx.y * 128;
  const long long col0 = (long long)blockIdx.x * 128;
  const int zo = blockIdx.z >> L, zi = blockIdx.z & ((1 << L) - 1);
  const us* Az = A + zo * sA0 + zi * sA1;
  const us* Bz = Bm + zo * sB0 + zi * sB1;

  // chunk c = kb*512 + mb*64 + qd*16 + mm -> row mb*16+mm, k = kb*32 + qd*8.
  // Thread t stages chunks t+256j (j=0..3): per wave one gld16 covers 64
  // consecutive chunks = contiguous 1 KB of LDS (HW lane-scatter rule).
  int offA[4], offB[4];
#pragma unroll
  for (int j = 0; j < 4; ++j) {
    const int c = t + 256 * j;
    const int kb = c >> 9, mb = (c >> 6) & 7, qd = (c >> 4) & 3, mm = c & 15;
    offA[j] = (int)((row0 + mb * 16 + mm) * (long long)lda + kb * 32 + qd * 8);
    offB[j] = (int)((col0 + mb * 16 + mm) * (long long)ldb + kb * 32 + qd * 8);
  }

  f4v acc[4][4];
#pragma unroll
  for (int r = 0; r < 4; ++r)
#pragma unroll
    for (int c = 0; c < 4; ++c) acc[r][c] = (f4v){0.f, 0.f, 0.f, 0.f};

  const int nk = K >> 6;
  const int fo = quad * 16 + m16;
  for (int i = 0; i < nk; ++i) {
    const int kof = i << 6;
#pragma unroll
    for (int j = 0; j < 4; ++j) {
      us* la = (us*)As + (256 * j + wv * 64) * 8;  // wave-uniform base
      us* lb = (us*)Bs + (256 * j + wv * 64) * 8;
      gld16(Az + offA[j] + kof, la);
      gld16(Bz + offB[j] + kof, lb);
    }
    __syncthreads();  // drains vmcnt(0): staged data visible
#pragma unroll
    for (int kb = 0; kb < 2; ++kb) {
      s8v af[4], bf[4];
#pragma unroll
      for (int r = 0; r < 4; ++r)
        af[r] = *(const s8v*)&As[(kb * 512 + ((wv & 1) * 4 + r) * 64 + fo) * 8];
#pragma unroll
      for (int c = 0; c < 4; ++c)
        bf[c] = *(const s8v*)&Bs[(kb * 512 + ((wv >> 1) * 4 + c) * 64 + fo) * 8];
#pragma unroll
      for (int r = 0; r < 4; ++r)
#pragma unroll
        for (int c = 0; c < 4; ++c)
          acc[r][c] = __builtin_amdgcn_mfma_f32_16x16x32_bf16(af[r], bf[c], acc[r][c], 0, 0, 0);
    }
    __syncthreads();  // LDS reads drained before next overwrite
  }

  // Epilogue. C/D layout: col = lane&15, row = quad*4 + reg (m89-verified).
  const float* bz = bias ? (bias + zi * sbias) : (const float*)0;
#pragma unroll
  for (int r = 0; r < 4; ++r) {
    const long long gr0 = row0 + (wv & 1) * 64 + r * 16 + quad * 4;
#pragma unroll
    for (int c = 0; c < 4; ++c) {
      const long long gc = col0 + (wv >> 1) * 64 + c * 16 + m16;
      if (EPI == 1) {
        us* C = (us*)Cv + zo * sC0 + zi * sC1;
        const float bb = bz ? bz[gc] : 0.f;
#pragma unroll
        for (int g = 0; g < 4; ++g)
          C[(gr0 + g) * (long long)ldc + gc] = f2b(acc[r][c][g] * alpha + bb);
      } else if (EPI == 2) {
        us* C = (us*)Cv + zo * sC0 + zi * sC1;
        const float bb = bz ? bz[gc] : 0.f;
        us4v pk;
#pragma unroll
        for (int g = 0; g < 4; ++g) pk[g] = f2b(acc[r][c][g] * alpha + bb);
        *(us4v*)&C[gc * (long long)ldc + gr0] = pk;  // 8B store, gr0 % 4 == 0
      } else {  // EPI 4
        float* C = (float*)Cv + zo * sC0 + zi * sC1;
        float* p = C + gr0 * ldc + gc;
#pragma unroll
        for (int g = 0; g < 4; ++g) p[(long long)g * ldc] += acc[r][c][g] * alpha;
      }
    }
  }
}

// In-place row softmax on bf16, 2048 cols; one block (256 thr) per row.
__global__ __launch_bounds__(256) void softmax_bf16(us* __restrict__ sc) {
  const int t = threadIdx.x;
  us* p = sc + ((long long)blockIdx.y * 2048 + (long long)blockIdx.x) * 2048;
  const us8v raw = *(const us8v*)(p + t * 8);
  float vals[8];
  float m = -1e30f;
#pragma unroll
  for (int u = 0; u < 8; ++u) {
    vals[u] = b2f(raw[u]);
    m = fmaxf(m, vals[u]);
  }
#pragma unroll
  for (int off = 32; off; off >>= 1) m = fmaxf(m, __shfl_xor(m, off, 64));
  __shared__ float redm[4], reds[4];
  if ((t & 63) == 0) redm[t >> 6] = m;
  __syncthreads();
  m = fmaxf(fmaxf(redm[0], redm[1]), fmaxf(redm[2], redm[3]));
  float s = 0.f;
#pragma unroll
  for (int u = 0; u < 8; ++u) {
    vals[u] = __expf(vals[u] - m);
    s += vals[u];
  }
#pragma unroll
  for (int off = 32; off; off >>= 1) s += __shfl_xor(s, off, 64);
  if ((t & 63) == 0) reds[t >> 6] = s;
  __syncthreads();
  s = reds[0] + reds[1] + reds[2] + reds[3];
  const float inv = 1.f / s;
  us8v o;
#pragma unroll
  for (int u = 0; u < 8; ++u) o[u] = f2b(vals[u] * inv);
  *(us8v*)(p + t * 8) = o;
}

__global__ __launch_bounds__(256) void conv_bf16(const float* __restrict__ in,
                                                 us* __restrict__ out, int n4) {
  const int i = blockIdx.x * 256 + threadIdx.x;
  if (i < n4) {
    const float4 f = ((const float4*)in)[i];
    us4v o;
    o[0] = f2b(f.x); o[1] = f2b(f.y); o[2] = f2b(f.z); o[3] = f2b(f.w);
    ((us4v*)out)[i] = o;
  }
}

// in [Z][R][C] fp32 -> out [Z][C][R] bf16
__global__ __launch_bounds__(256) void conv_transpose(const float* __restrict__ in,
                                                      us* __restrict__ out,
                                                      int R, int C) {
  __shared__ float tile[32][33];
  const int tx = threadIdx.x & 31, ty = threadIdx.x >> 5;
  const long long zo = (long long)blockIdx.z * R * C;
  const int r0 = blockIdx.y * 32, c0 = blockIdx.x * 32;
#pragma unroll
  for (int j = 0; j < 4; ++j)
    tile[ty + 8 * j][tx] = in[zo + (long long)(r0 + ty + 8 * j) * C + c0 + tx];
  __syncthreads();
#pragma unroll
  for (int j = 0; j < 4; ++j)
    out[zo + (long long)(c0 + ty + 8 * j) * R + r0 + tx] = f2b(tile[tx][ty + 8 * j]);
}

__global__ __launch_bounds__(256) void init_out_kernel(float* __restrict__ out,
                                                       const float* __restrict__ bp,
                                                       int total) {
  const int i = blockIdx.x * 256 + threadIdx.x;
  if (i < total) out[i] = bp[i & 511];  // D=512
}

extern "C" void kernel_launch(void* const* d_in, const int* in_sizes, int n_in,
                              void* d_out, int out_size, void* d_ws, size_t ws_size,
                              hipStream_t stream) {
  constexpr int Bb = 4, S = 2048, D = 512, H = 8, E = 512, HE = 4096;
  const float* x  = (const float*)d_in[0];
  const float* Wq = (const float*)d_in[1];
  const float* bq = (const float*)d_in[2];
  const float* Wk = (const float*)d_in[3];
  const float* bk = (const float*)d_in[4];
  const float* Wv = (const float*)d_in[5];
  const float* bv = (const float*)d_in[6];
  const float* Wp = (const float*)d_in[7];
  const float* bp = (const float*)d_in[8];
  float* out = (float*)d_out;

  const long long SE = (long long)S * E, SS = (long long)S * S;
  const long long SD = (long long)S * D, ED = (long long)E * D;

  // Fixed region: xh + 4 transposed weight planes (25.2 MB).
  us* xh  = (us*)d_ws;            // B*S*D      = 4,194,304 us
  us* WqT = xh + 4194304;         // H*E*D      = 2,097,152 us
  us* WkT = WqT + 2097152;
  us* WvT = WkT + 2097152;
  us* WpT = WvT + 2097152;        // D*HE
  us* dyn = WpT + 2097152;

  // Head-chunk size from ws_size (HC=2 fits in R2's proven 159.4 MB).
  const size_t fixedB = (size_t)(4194304 + 4 * 2097152) * 2;
  int HC = 8;
  while (HC > 1) {
    const size_t need = fixedB + (size_t)HC * (4 * (size_t)Bb * SE + (size_t)Bb * SS) * 2;
    if (need <= ws_size) break;
    HC >>= 1;
  }
  const int L = (HC == 8) ? 3 : (HC == 4) ? 2 : (HC == 2) ? 1 : 0;
  const int BHC = Bb * HC;

  us* qh = dyn;                       // [b*HC+hc][S][E]
  us* kh = qh + (size_t)BHC * SE;
  us* vT = kh + (size_t)BHC * SE;     // [b*HC+hc][E][S]
  us* oh = vT + (size_t)BHC * SE;     // [b][S][HC][E]  (interleaved for out-proj)
  us* sc = oh + (size_t)BHC * SE;     // [b*HC+hc][S][S]

  const dim3 tb(256);
  init_out_kernel<<<dim3((Bb * S * D + 255) / 256), tb, 0, stream>>>(out, bp, Bb * S * D);
  conv_bf16<<<dim3(4194304 / 4 / 256), tb, 0, stream>>>(x, xh, 4194304 / 4);
  conv_transpose<<<dim3(E / 32, D / 32, H), tb, 0, stream>>>(Wq, WqT, D, E);
  conv_transpose<<<dim3(E / 32, D / 32, H), tb, 0, stream>>>(Wk, WkT, D, E);
  conv_transpose<<<dim3(E / 32, D / 32, H), tb, 0, stream>>>(Wv, WvT, D, E);
  conv_transpose<<<dim3(D / 32, HE / 32, 1), tb, 0, stream>>>(Wp, WpT, HE, D);

  const float aS = 0.044194173824159216f;  // 1/sqrt(512)
  const dim3 gP(4, 16, BHC), gS(16, 16, BHC);

  for (int h0 = 0; h0 < H; h0 += HC) {
    // Q/K projections -> bf16 [z][S][E]
    gemm_nt<1><<<gP, tb, 0, stream>>>(
        xh, D, SD, 0, WqT + (long long)h0 * ED, D, 0, ED, bq + h0 * E, E,
        qh, E, (long long)HC * SE, SE, D, 1.f, L);
    gemm_nt<1><<<gP, tb, 0, stream>>>(
        xh, D, SD, 0, WkT + (long long)h0 * ED, D, 0, ED, bk + h0 * E, E,
        kh, E, (long long)HC * SE, SE, D, 1.f, L);
    // V projection, transposed out -> [z][E][S]   (FIX: sC1 = E*S, was E*S*D)
    gemm_nt<2><<<gP, tb, 0, stream>>>(
        xh, D, SD, 0, WvT + (long long)h0 * ED, D, 0, ED, bv + h0 * E, E,
        vT, S, (long long)HC * E * S, (long long)E * S, D, 1.f, L);
    // scores = (Q K^T)/sqrt(E) -> bf16 [z][S][S]
    gemm_nt<1><<<gS, tb, 0, stream>>>(
        qh, E, (long long)HC * SE, SE, kh, E, (long long)HC * SE, SE, nullptr, 0,
        sc, S, (long long)HC * SS, SS, E, aS, L);
    softmax_bf16<<<dim3(S, BHC), tb, 0, stream>>>(sc);
    // O = P @ V  (B operand = V^T slice [E][S]) -> oh [b][S][HC][E]
    gemm_nt<1><<<gP, tb, 0, stream>>>(
        sc, S, (long long)HC * SS, SS, vT, S, (long long)HC * E * S, (long long)E * S,
        nullptr, 0, oh, HC * E, (long long)S * HC * E, E, S, 1.f, L);
    // out += O @ Wp-chunk  (K = HC*E), z = batch only
    gemm_nt<4><<<dim3(4, 16, Bb), tb, 0, stream>>>(
        oh, HC * E, (long long)S * HC * E, 0, WpT + (long long)h0 * E, HE, 0, 0,
        nullptr, 0, out, D, SD, 0, HC * E, 1.f, 0);
  }
}

// Round 5
// 1159.726 us; speedup vs baseline: 5.7289x; 1.0376x over previous
//
#include <hip/hip_runtime.h>

// R5: BK=32 / 16KB-LDS GEMM core (m97-exact: 16 MFMA + 4 gld16 per iter,
// ~8 blocks/CU for cross-block barrier-latency hiding), HC=4 via oh<-qh
// aliasing (20 launches), wave-per-row barrier-free softmax.

typedef short s8v __attribute__((ext_vector_type(8)));   // 8 bf16 = 4 VGPRs
typedef float f4v __attribute__((ext_vector_type(4)));
typedef unsigned short us;
typedef us us4v __attribute__((ext_vector_type(4)));
typedef us us8v __attribute__((ext_vector_type(8)));

__device__ inline us f2b(float f) {  // fp32 -> bf16 RNE
  union { float f; unsigned u; } v; v.f = f;
  unsigned r = v.u + 0x7FFFu + ((v.u >> 16) & 1u);
  return (us)(r >> 16);
}
__device__ inline float b2f(us b) {
  union { unsigned u; float f; } v; v.u = ((unsigned)b) << 16;
  return v.f;
}

// async global->LDS, 16 B per lane; LDS dest = wave-uniform base + lane*16.
__device__ inline void gld16(const us* g, us* l) {
  __builtin_amdgcn_global_load_lds(
      (const __attribute__((address_space(1))) void*)g,
      (__attribute__((address_space(3))) void*)l, 16, 0, 0);
}

// NT GEMM: C = alpha * A @ B^T (+bias), A[M,K] (lda), B[N,K] (ldb), bf16.
// z = (zo<<L)|zi -> offsets zo*s?0 + zi*s?1 (batch x head-chunk in one grid).
// EPI: 1 = bf16 out (+bias, *alpha); 2 = bf16 transposed out (V^T);
//      4 = fp32 accumulate out.
template <int EPI>
__global__ __launch_bounds__(256, 4) void gemm_nt(
    const us* __restrict__ A, int lda, long long sA0, long long sA1,
    const us* __restrict__ Bm, int ldb, long long sB0, long long sB1,
    const float* __restrict__ bias, long long sbias,
    void* __restrict__ Cv, int ldc, long long sC0, long long sC1,
    int K, float alpha, int L) {
  __shared__ us As[4096];  // 128 rows x 32 k, fragment-linear: 512 chunks x 16B
  __shared__ us Bs[4096];
  const int t = threadIdx.x;
  const int wv = t >> 6, ln = t & 63;
  const int m16 = ln & 15, quad = ln >> 4;
  const long long row0 = (long long)blockIdx.y * 128;
  const long long col0 = (long long)blockIdx.x * 128;
  const int zo = blockIdx.z >> L, zi = blockIdx.z & ((1 << L) - 1);
  const us* Az = A + zo * sA0 + zi * sA1;
  const us* Bz = Bm + zo * sB0 + zi * sB1;

  // chunk c = mb*64 + qd*16 + mm -> row mb*16+mm, k = qd*8 (512 chunks/matrix).
  // Thread t stages chunks t and t+256: per wave one gld16 covers 64
  // consecutive chunks = contiguous 1 KB of LDS (HW lane-scatter rule).
  int offA[2], offB[2];
#pragma unroll
  for (int j = 0; j < 2; ++j) {
    const int c = t + 256 * j;
    const int mb = c >> 6, qd = (c >> 4) & 3, mm = c & 15;
    offA[j] = (int)((row0 + mb * 16 + mm) * (long long)lda + qd * 8);
    offB[j] = (int)((col0 + mb * 16 + mm) * (long long)ldb + qd * 8);
  }

  f4v acc[4][4];
#pragma unroll
  for (int r = 0; r < 4; ++r)
#pragma unroll
    for (int c = 0; c < 4; ++c) acc[r][c] = (f4v){0.f, 0.f, 0.f, 0.f};

  const int nk = K >> 5;
  const int fo = quad * 16 + m16;  // chunk within a 16-row group
  for (int i = 0; i < nk; ++i) {
    const int kof = i << 5;
#pragma unroll
    for (int j = 0; j < 2; ++j) {
      us* la = (us*)As + (256 * j + wv * 64) * 8;  // wave-uniform base
      us* lb = (us*)Bs + (256 * j + wv * 64) * 8;
      gld16(Az + offA[j] + kof, la);
      gld16(Bz + offB[j] + kof, lb);
    }
    __syncthreads();  // drains vmcnt(0): staged data visible
    s8v af[4], bf[4];
#pragma unroll
    for (int r = 0; r < 4; ++r)
      af[r] = *(const s8v*)&As[(((wv & 1) * 4 + r) * 64 + fo) * 8];
#pragma unroll
    for (int c = 0; c < 4; ++c)
      bf[c] = *(const s8v*)&Bs[(((wv >> 1) * 4 + c) * 64 + fo) * 8];
#pragma unroll
    for (int r = 0; r < 4; ++r)
#pragma unroll
      for (int c = 0; c < 4; ++c)
        acc[r][c] = __builtin_amdgcn_mfma_f32_16x16x32_bf16(af[r], bf[c], acc[r][c], 0, 0, 0);
    __syncthreads();  // LDS reads drained before next overwrite
  }

  // Epilogue. C/D layout: col = lane&15, row = quad*4 + reg (m89-verified).
  const float* bz = bias ? (bias + zi * sbias) : (const float*)0;
#pragma unroll
  for (int r = 0; r < 4; ++r) {
    const long long gr0 = row0 + (wv & 1) * 64 + r * 16 + quad * 4;
#pragma unroll
    for (int c = 0; c < 4; ++c) {
      const long long gc = col0 + (wv >> 1) * 64 + c * 16 + m16;
      if (EPI == 1) {
        us* C = (us*)Cv + zo * sC0 + zi * sC1;
        const float bb = bz ? bz[gc] : 0.f;
#pragma unroll
        for (int g = 0; g < 4; ++g)
          C[(gr0 + g) * (long long)ldc + gc] = f2b(acc[r][c][g] * alpha + bb);
      } else if (EPI == 2) {
        us* C = (us*)Cv + zo * sC0 + zi * sC1;
        const float bb = bz ? bz[gc] : 0.f;
        us4v pk;
#pragma unroll
        for (int g = 0; g < 4; ++g) pk[g] = f2b(acc[r][c][g] * alpha + bb);
        *(us4v*)&C[gc * (long long)ldc + gr0] = pk;  // 8B store, gr0 % 4 == 0
      } else {  // EPI 4
        float* C = (float*)Cv + zo * sC0 + zi * sC1;
        float* p = C + gr0 * ldc + gc;
#pragma unroll
        for (int g = 0; g < 4; ++g) p[(long long)g * ldc] += acc[r][c][g] * alpha;
      }
    }
  }
}

// In-place row softmax on bf16, 2048 cols. One wave per row, 4 rows/block,
// shuffle-only reduction (no LDS, no barriers).
__global__ __launch_bounds__(256) void softmax_bf16(us* __restrict__ sc) {
  const int w = threadIdx.x >> 6, ln = threadIdx.x & 63;
  us* p = sc + ((long long)blockIdx.y * 2048 + (long long)(blockIdx.x * 4 + w)) * 2048;
  us8v raw[4];
  float vals[32];
#pragma unroll
  for (int j = 0; j < 4; ++j) raw[j] = *(const us8v*)(p + j * 512 + ln * 8);
  float m = -1e30f;
#pragma unroll
  for (int j = 0; j < 4; ++j)
#pragma unroll
    for (int u = 0; u < 8; ++u) {
      vals[j * 8 + u] = b2f(raw[j][u]);
      m = fmaxf(m, vals[j * 8 + u]);
    }
#pragma unroll
  for (int off = 32; off; off >>= 1) m = fmaxf(m, __shfl_xor(m, off, 64));
  float s = 0.f;
#pragma unroll
  for (int u = 0; u < 32; ++u) {
    vals[u] = __expf(vals[u] - m);
    s += vals[u];
  }
#pragma unroll
  for (int off = 32; off; off >>= 1) s += __shfl_xor(s, off, 64);
  const float inv = 1.f / s;
#pragma unroll
  for (int j = 0; j < 4; ++j) {
    us8v o;
#pragma unroll
    for (int u = 0; u < 8; ++u) o[u] = f2b(vals[j * 8 + u] * inv);
    *(us8v*)(p + j * 512 + ln * 8) = o;
  }
}

__global__ __launch_bounds__(256) void conv_bf16(const float* __restrict__ in,
                                                 us* __restrict__ out, int n4) {
  const int i = blockIdx.x * 256 + threadIdx.x;
  if (i < n4) {
    const float4 f = ((const float4*)in)[i];
    us4v o;
    o[0] = f2b(f.x); o[1] = f2b(f.y); o[2] = f2b(f.z); o[3] = f2b(f.w);
    ((us4v*)out)[i] = o;
  }
}

// in [Z][R][C] fp32 -> out [Z][C][R] bf16
__global__ __launch_bounds__(256) void conv_transpose(const float* __restrict__ in,
                                                      us* __restrict__ out,
                                                      int R, int C) {
  __shared__ float tile[32][33];
  const int tx = threadIdx.x & 31, ty = threadIdx.x >> 5;
  const long long zo = (long long)blockIdx.z * R * C;
  const int r0 = blockIdx.y * 32, c0 = blockIdx.x * 32;
#pragma unroll
  for (int j = 0; j < 4; ++j)
    tile[ty + 8 * j][tx] = in[zo + (long long)(r0 + ty + 8 * j) * C + c0 + tx];
  __syncthreads();
#pragma unroll
  for (int j = 0; j < 4; ++j)
    out[zo + (long long)(c0 + ty + 8 * j) * R + r0 + tx] = f2b(tile[tx][ty + 8 * j]);
}

__global__ __launch_bounds__(256) void init_out_kernel(float* __restrict__ out,
                                                       const float* __restrict__ bp,
                                                       int total) {
  const int i = blockIdx.x * 256 + threadIdx.x;
  if (i < total) out[i] = bp[i & 511];  // D=512
}

extern "C" void kernel_launch(void* const* d_in, const int* in_sizes, int n_in,
                              void* d_out, int out_size, void* d_ws, size_t ws_size,
                              hipStream_t stream) {
  constexpr int Bb = 4, S = 2048, D = 512, H = 8, E = 512, HE = 4096;
  const float* x  = (const float*)d_in[0];
  const float* Wq = (const float*)d_in[1];
  const float* bq = (const float*)d_in[2];
  const float* Wk = (const float*)d_in[3];
  const float* bk = (const float*)d_in[4];
  const float* Wv = (const float*)d_in[5];
  const float* bv = (const float*)d_in[6];
  const float* Wp = (const float*)d_in[7];
  const float* bp = (const float*)d_in[8];
  float* out = (float*)d_out;

  const long long SE = (long long)S * E, SS = (long long)S * S;
  const long long SD = (long long)S * D, ED = (long long)E * D;

  // Fixed region: xh + 4 transposed weight planes (25.2 MB).
  us* xh  = (us*)d_ws;            // B*S*D      = 4,194,304 us
  us* WqT = xh + 4194304;         // H*E*D      = 2,097,152 us
  us* WkT = WqT + 2097152;
  us* WvT = WkT + 2097152;
  us* WpT = WvT + 2097152;        // D*HE
  us* dyn = WpT + 2097152;

  // Head-chunk size. oh aliases qh (qh dead after scores GEMM), so per-HC
  // footprint = 3 qkv planes + sc. HC=4 -> 260.0 MB, fits 256 MiB ws.
  const size_t fixedB = (size_t)(4194304 + 4 * 2097152) * 2;
  int HC = 8;
  while (HC > 1) {
    const size_t need = fixedB + (size_t)HC * (3 * (size_t)Bb * SE + (size_t)Bb * SS) * 2;
    if (need <= ws_size) break;
    HC >>= 1;
  }
  const int L = (HC == 8) ? 3 : (HC == 4) ? 2 : (HC == 2) ? 1 : 0;
  const int BHC = Bb * HC;

  us* qh = dyn;                       // [b*HC+hc][S][E]
  us* kh = qh + (size_t)BHC * SE;
  us* vT = kh + (size_t)BHC * SE;     // [b*HC+hc][E][S]
  us* sc = vT + (size_t)BHC * SE;     // [b*HC+hc][S][S]
  us* oh = qh;                        // alias: [b][S][HC][E], qh dead by PV

  const dim3 tb(256);
  init_out_kernel<<<dim3((Bb * S * D + 255) / 256), tb, 0, stream>>>(out, bp, Bb * S * D);
  conv_bf16<<<dim3(4194304 / 4 / 256), tb, 0, stream>>>(x, xh, 4194304 / 4);
  conv_transpose<<<dim3(E / 32, D / 32, H), tb, 0, stream>>>(Wq, WqT, D, E);
  conv_transpose<<<dim3(E / 32, D / 32, H), tb, 0, stream>>>(Wk, WkT, D, E);
  conv_transpose<<<dim3(E / 32, D / 32, H), tb, 0, stream>>>(Wv, WvT, D, E);
  conv_transpose<<<dim3(D / 32, HE / 32, 1), tb, 0, stream>>>(Wp, WpT, HE, D);

  const float aS = 0.044194173824159216f;  // 1/sqrt(512)
  const dim3 gP(4, 16, BHC), gS(16, 16, BHC);

  for (int h0 = 0; h0 < H; h0 += HC) {
    // Q/K projections -> bf16 [z][S][E]
    gemm_nt<1><<<gP, tb, 0, stream>>>(
        xh, D, SD, 0, WqT + (long long)h0 * ED, D, 0, ED, bq + h0 * E, E,
        qh, E, (long long)HC * SE, SE, D, 1.f, L);
    gemm_nt<1><<<gP, tb, 0, stream>>>(
        xh, D, SD, 0, WkT + (long long)h0 * ED, D, 0, ED, bk + h0 * E, E,
        kh, E, (long long)HC * SE, SE, D, 1.f, L);
    // V projection, transposed out -> [z][E][S]
    gemm_nt<2><<<gP, tb, 0, stream>>>(
        xh, D, SD, 0, WvT + (long long)h0 * ED, D, 0, ED, bv + h0 * E, E,
        vT, S, (long long)HC * E * S, (long long)E * S, D, 1.f, L);
    // scores = (Q K^T)/sqrt(E) -> bf16 [z][S][S]
    gemm_nt<1><<<gS, tb, 0, stream>>>(
        qh, E, (long long)HC * SE, SE, kh, E, (long long)HC * SE, SE, nullptr, 0,
        sc, S, (long long)HC * SS, SS, E, aS, L);
    softmax_bf16<<<dim3(S / 4, BHC), tb, 0, stream>>>(sc);
    // O = P @ V  (B operand = V^T slice [E][S]) -> oh [b][S][HC][E]
    gemm_nt<1><<<gP, tb, 0, stream>>>(
        sc, S, (long long)HC * SS, SS, vT, S, (long long)HC * E * S, (long long)E * S,
        nullptr, 0, oh, HC * E, (long long)S * HC * E, E, S, 1.f, L);
    // out += O @ Wp-chunk  (K = HC*E), z = batch only
    gemm_nt<4><<<dim3(4, 16, Bb), tb, 0, stream>>>(
        oh, HC * E, (long long)S * HC * E, 0, WpT + (long long)h0 * E, HE, 0, 0,
        nullptr, 0, out, D, SD, 0, HC * E, 1.f, 0);
  }
}

// Round 6
// 1125.639 us; speedup vs baseline: 5.9024x; 1.0303x over previous
//
#include <hip/hip_runtime.h>

// R6: R5 + (a) XCD-aware flat-block swizzle so each XCD owns a contiguous
// z-range (L2-resident operand slices, ~200 vs ~900 cyc load latency), and
// (b) LDS double-buffer (BK=32 x2 = 32KB): next tile's global_load_lds is in
// flight during the whole compute phase, one barrier per iter.

typedef short s8v __attribute__((ext_vector_type(8)));   // 8 bf16 = 4 VGPRs
typedef float f4v __attribute__((ext_vector_type(4)));
typedef unsigned short us;
typedef us us4v __attribute__((ext_vector_type(4)));
typedef us us8v __attribute__((ext_vector_type(8)));

__device__ inline us f2b(float f) {  // fp32 -> bf16 RNE
  union { float f; unsigned u; } v; v.f = f;
  unsigned r = v.u + 0x7FFFu + ((v.u >> 16) & 1u);
  return (us)(r >> 16);
}
__device__ inline float b2f(us b) {
  union { unsigned u; float f; } v; v.u = ((unsigned)b) << 16;
  return v.f;
}

// async global->LDS, 16 B per lane; LDS dest = wave-uniform base + lane*16.
__device__ inline void gld16(const us* g, us* l) {
  __builtin_amdgcn_global_load_lds(
      (const __attribute__((address_space(1))) void*)g,
      (__attribute__((address_space(3))) void*)l, 16, 0, 0);
}

// NT GEMM: C = alpha * A @ B^T (+bias), A[M,K] (lda), B[N,K] (ldb), bf16.
// z = (zo<<L)|zi -> offsets zo*s?0 + zi*s?1 (batch x head-chunk in one grid).
// EPI: 1 = bf16 out (+bias, *alpha); 2 = bf16 transposed out (V^T);
//      4 = fp32 accumulate out.
template <int EPI>
__global__ __launch_bounds__(256, 4) void gemm_nt(
    const us* __restrict__ A, int lda, long long sA0, long long sA1,
    const us* __restrict__ Bm, int ldb, long long sB0, long long sB1,
    const float* __restrict__ bias, long long sbias,
    void* __restrict__ Cv, int ldc, long long sC0, long long sC1,
    int K, float alpha, int L) {
  __shared__ us As[2][4096];  // 128 rows x 32 k per buf, fragment-linear
  __shared__ us Bs[2][4096];
  const int t = threadIdx.x;
  const int wv = t >> 6, ln = t & 63;
  const int m16 = ln & 15, quad = ln >> 4;

  // XCD-aware swizzle: dispatch assigns block flat%8 -> XCD (heuristic).
  // Remap so XCD k owns the contiguous work range [k*per, (k+1)*per) ->
  // each XCD sees only ~2 z-slices -> operand slices stay L2-resident.
  const int gx = gridDim.x, gxy = gx * gridDim.y;
  const int nblk = gxy * gridDim.z;
  const int flat = blockIdx.x + gx * blockIdx.y + gxy * blockIdx.z;
  const int per = nblk >> 3;
  const int nid = (flat & 7) * per + (flat >> 3);
  const int bz = nid / gxy, rem = nid % gxy;
  const int by = rem / gx, bx = rem % gx;

  const long long row0 = (long long)by * 128;
  const long long col0 = (long long)bx * 128;
  const int zo = bz >> L, zi = bz & ((1 << L) - 1);
  const us* Az = A + zo * sA0 + zi * sA1;
  const us* Bz = Bm + zo * sB0 + zi * sB1;

  // chunk c = mb*64 + qd*16 + mm -> row mb*16+mm, k = qd*8 (512 chunks/tile).
  // Thread t stages chunks t and t+256: per wave one gld16 covers 64
  // consecutive chunks = contiguous 1 KB of LDS (HW lane-scatter rule).
  int offA[2], offB[2];
#pragma unroll
  for (int j = 0; j < 2; ++j) {
    const int c = t + 256 * j;
    const int mb = c >> 6, qd = (c >> 4) & 3, mm = c & 15;
    offA[j] = (int)((row0 + mb * 16 + mm) * (long long)lda + qd * 8);
    offB[j] = (int)((col0 + mb * 16 + mm) * (long long)ldb + qd * 8);
  }

  f4v acc[4][4];
#pragma unroll
  for (int r = 0; r < 4; ++r)
#pragma unroll
    for (int c = 0; c < 4; ++c) acc[r][c] = (f4v){0.f, 0.f, 0.f, 0.f};

  const int nk = K >> 5;
  const int fo = quad * 16 + m16;  // chunk within a 16-row group

  // prologue: stage k-tile 0 into buffer 0
#pragma unroll
  for (int j = 0; j < 2; ++j) {
    gld16(Az + offA[j], (us*)As[0] + (256 * j + wv * 64) * 8);
    gld16(Bz + offB[j], (us*)Bs[0] + (256 * j + wv * 64) * 8);
  }

  for (int i = 0; i < nk; ++i) {
    __syncthreads();  // drains vmcnt: buf (i&1) staged; prev reads done
    const int cur = i & 1;
    if (i + 1 < nk) {  // prefetch next tile into alternate buffer
      const int kof = (i + 1) << 5;
#pragma unroll
      for (int j = 0; j < 2; ++j) {
        gld16(Az + offA[j] + kof, (us*)As[cur ^ 1] + (256 * j + wv * 64) * 8);
        gld16(Bz + offB[j] + kof, (us*)Bs[cur ^ 1] + (256 * j + wv * 64) * 8);
      }
    }
    s8v af[4], bf[4];
#pragma unroll
    for (int r = 0; r < 4; ++r)
      af[r] = *(const s8v*)&As[cur][(((wv & 1) * 4 + r) * 64 + fo) * 8];
#pragma unroll
    for (int c = 0; c < 4; ++c)
      bf[c] = *(const s8v*)&Bs[cur][(((wv >> 1) * 4 + c) * 64 + fo) * 8];
#pragma unroll
    for (int r = 0; r < 4; ++r)
#pragma unroll
      for (int c = 0; c < 4; ++c)
        acc[r][c] = __builtin_amdgcn_mfma_f32_16x16x32_bf16(af[r], bf[c], acc[r][c], 0, 0, 0);
  }

  // Epilogue. C/D layout: col = lane&15, row = quad*4 + reg (m89-verified).
  const float* bz_ = bias ? (bias + zi * sbias) : (const float*)0;
#pragma unroll
  for (int r = 0; r < 4; ++r) {
    const long long gr0 = row0 + (wv & 1) * 64 + r * 16 + quad * 4;
#pragma unroll
    for (int c = 0; c < 4; ++c) {
      const long long gc = col0 + (wv >> 1) * 64 + c * 16 + m16;
      if (EPI == 1) {
        us* C = (us*)Cv + zo * sC0 + zi * sC1;
        const float bb = bz_ ? bz_[gc] : 0.f;
#pragma unroll
        for (int g = 0; g < 4; ++g)
          C[(gr0 + g) * (long long)ldc + gc] = f2b(acc[r][c][g] * alpha + bb);
      } else if (EPI == 2) {
        us* C = (us*)Cv + zo * sC0 + zi * sC1;
        const float bb = bz_ ? bz_[gc] : 0.f;
        us4v pk;
#pragma unroll
        for (int g = 0; g < 4; ++g) pk[g] = f2b(acc[r][c][g] * alpha + bb);
        *(us4v*)&C[gc * (long long)ldc + gr0] = pk;  // 8B store, gr0 % 4 == 0
      } else {  // EPI 4
        float* C = (float*)Cv + zo * sC0 + zi * sC1;
        float* p = C + gr0 * ldc + gc;
#pragma unroll
        for (int g = 0; g < 4; ++g) p[(long long)g * ldc] += acc[r][c][g] * alpha;
      }
    }
  }
}

// In-place row softmax on bf16, 2048 cols. One wave per row, 4 rows/block,
// shuffle-only reduction (no LDS, no barriers).
__global__ __launch_bounds__(256) void softmax_bf16(us* __restrict__ sc) {
  const int w = threadIdx.x >> 6, ln = threadIdx.x & 63;
  us* p = sc + ((long long)blockIdx.y * 2048 + (long long)(blockIdx.x * 4 + w)) * 2048;
  us8v raw[4];
  float vals[32];
#pragma unroll
  for (int j = 0; j < 4; ++j) raw[j] = *(const us8v*)(p + j * 512 + ln * 8);
  float m = -1e30f;
#pragma unroll
  for (int j = 0; j < 4; ++j)
#pragma unroll
    for (int u = 0; u < 8; ++u) {
      vals[j * 8 + u] = b2f(raw[j][u]);
      m = fmaxf(m, vals[j * 8 + u]);
    }
#pragma unroll
  for (int off = 32; off; off >>= 1) m = fmaxf(m, __shfl_xor(m, off, 64));
  float s = 0.f;
#pragma unroll
  for (int u = 0; u < 32; ++u) {
    vals[u] = __expf(vals[u] - m);
    s += vals[u];
  }
#pragma unroll
  for (int off = 32; off; off >>= 1) s += __shfl_xor(s, off, 64);
  const float inv = 1.f / s;
#pragma unroll
  for (int j = 0; j < 4; ++j) {
    us8v o;
#pragma unroll
    for (int u = 0; u < 8; ++u) o[u] = f2b(vals[j * 8 + u] * inv);
    *(us8v*)(p + j * 512 + ln * 8) = o;
  }
}

__global__ __launch_bounds__(256) void conv_bf16(const float* __restrict__ in,
                                                 us* __restrict__ out, int n4) {
  const int i = blockIdx.x * 256 + threadIdx.x;
  if (i < n4) {
    const float4 f = ((const float4*)in)[i];
    us4v o;
    o[0] = f2b(f.x); o[1] = f2b(f.y); o[2] = f2b(f.z); o[3] = f2b(f.w);
    ((us4v*)out)[i] = o;
  }
}

// in [Z][R][C] fp32 -> out [Z][C][R] bf16
__global__ __launch_bounds__(256) void conv_transpose(const float* __restrict__ in,
                                                      us* __restrict__ out,
                                                      int R, int C) {
  __shared__ float tile[32][33];
  const int tx = threadIdx.x & 31, ty = threadIdx.x >> 5;
  const long long zo = (long long)blockIdx.z * R * C;
  const int r0 = blockIdx.y * 32, c0 = blockIdx.x * 32;
#pragma unroll
  for (int j = 0; j < 4; ++j)
    tile[ty + 8 * j][tx] = in[zo + (long long)(r0 + ty + 8 * j) * C + c0 + tx];
  __syncthreads();
#pragma unroll
  for (int j = 0; j < 4; ++j)
    out[zo + (long long)(c0 + ty + 8 * j) * R + r0 + tx] = f2b(tile[tx][ty + 8 * j]);
}

__global__ __launch_bounds__(256) void init_out_kernel(float* __restrict__ out,
                                                       const float* __restrict__ bp,
                                                       int total) {
  const int i = blockIdx.x * 256 + threadIdx.x;
  if (i < total) out[i] = bp[i & 511];  // D=512
}

extern "C" void kernel_launch(void* const* d_in, const int* in_sizes, int n_in,
                              void* d_out, int out_size, void* d_ws, size_t ws_size,
                              hipStream_t stream) {
  constexpr int Bb = 4, S = 2048, D = 512, H = 8, E = 512, HE = 4096;
  const float* x  = (const float*)d_in[0];
  const float* Wq = (const float*)d_in[1];
  const float* bq = (const float*)d_in[2];
  const float* Wk = (const float*)d_in[3];
  const float* bk = (const float*)d_in[4];
  const float* Wv = (const float*)d_in[5];
  const float* bv = (const float*)d_in[6];
  const float* Wp = (const float*)d_in[7];
  const float* bp = (const float*)d_in[8];
  float* out = (float*)d_out;

  const long long SE = (long long)S * E, SS = (long long)S * S;
  const long long SD = (long long)S * D, ED = (long long)E * D;

  // Fixed region: xh + 4 transposed weight planes (25.2 MB).
  us* xh  = (us*)d_ws;            // B*S*D      = 4,194,304 us
  us* WqT = xh + 4194304;         // H*E*D      = 2,097,152 us
  us* WkT = WqT + 2097152;
  us* WvT = WkT + 2097152;
  us* WpT = WvT + 2097152;        // D*HE
  us* dyn = WpT + 2097152;

  // Head-chunk size. oh aliases qh (qh dead after scores GEMM), so per-HC
  // footprint = 3 qkv planes + sc. HC=4 -> 260.0 MB, fits 256 MiB ws.
  const size_t fixedB = (size_t)(4194304 + 4 * 2097152) * 2;
  int HC = 8;
  while (HC > 1) {
    const size_t need = fixedB + (size_t)HC * (3 * (size_t)Bb * SE + (size_t)Bb * SS) * 2;
    if (need <= ws_size) break;
    HC >>= 1;
  }
  const int L = (HC == 8) ? 3 : (HC == 4) ? 2 : (HC == 2) ? 1 : 0;
  const int BHC = Bb * HC;

  us* qh = dyn;                       // [b*HC+hc][S][E]
  us* kh = qh + (size_t)BHC * SE;
  us* vT = kh + (size_t)BHC * SE;     // [b*HC+hc][E][S]
  us* sc = vT + (size_t)BHC * SE;     // [b*HC+hc][S][S]
  us* oh = qh;                        // alias: [b][S][HC][E], qh dead by PV

  const dim3 tb(256);
  init_out_kernel<<<dim3((Bb * S * D + 255) / 256), tb, 0, stream>>>(out, bp, Bb * S * D);
  conv_bf16<<<dim3(4194304 / 4 / 256), tb, 0, stream>>>(x, xh, 4194304 / 4);
  conv_transpose<<<dim3(E / 32, D / 32, H), tb, 0, stream>>>(Wq, WqT, D, E);
  conv_transpose<<<dim3(E / 32, D / 32, H), tb, 0, stream>>>(Wk, WkT, D, E);
  conv_transpose<<<dim3(E / 32, D / 32, H), tb, 0, stream>>>(Wv, WvT, D, E);
  conv_transpose<<<dim3(D / 32, HE / 32, 1), tb, 0, stream>>>(Wp, WpT, HE, D);

  const float aS = 0.044194173824159216f;  // 1/sqrt(512)
  const dim3 gP(4, 16, BHC), gS(16, 16, BHC);

  for (int h0 = 0; h0 < H; h0 += HC) {
    // Q/K projections -> bf16 [z][S][E]
    gemm_nt<1><<<gP, tb, 0, stream>>>(
        xh, D, SD, 0, WqT + (long long)h0 * ED, D, 0, ED, bq + h0 * E, E,
        qh, E, (long long)HC * SE, SE, D, 1.f, L);
    gemm_nt<1><<<gP, tb, 0, stream>>>(
        xh, D, SD, 0, WkT + (long long)h0 * ED, D, 0, ED, bk + h0 * E, E,
        kh, E, (long long)HC * SE, SE, D, 1.f, L);
    // V projection, transposed out -> [z][E][S]
    gemm_nt<2><<<gP, tb, 0, stream>>>(
        xh, D, SD, 0, WvT + (long long)h0 * ED, D, 0, ED, bv + h0 * E, E,
        vT, S, (long long)HC * E * S, (long long)E * S, D, 1.f, L);
    // scores = (Q K^T)/sqrt(E) -> bf16 [z][S][S]
    gemm_nt<1><<<gS, tb, 0, stream>>>(
        qh, E, (long long)HC * SE, SE, kh, E, (long long)HC * SE, SE, nullptr, 0,
        sc, S, (long long)HC * SS, SS, E, aS, L);
    softmax_bf16<<<dim3(S / 4, BHC), tb, 0, stream>>>(sc);
    // O = P @ V  (B operand = V^T slice [E][S]) -> oh [b][S][HC][E]
    gemm_nt<1><<<gP, tb, 0, stream>>>(
        sc, S, (long long)HC * SS, SS, vT, S, (long long)HC * E * S, (long long)E * S,
        nullptr, 0, oh, HC * E, (long long)S * HC * E, E, S, 1.f, L);
    // out += O @ Wp-chunk  (K = HC*E), z = batch only
    gemm_nt<4><<<dim3(4, 16, Bb), tb, 0, stream>>>(
        oh, HC * E, (long long)S * HC * E, 0, WpT + (long long)h0 * E, HE, 0, 0,
        nullptr, 0, out, D, SD, 0, HC * E, 1.f, 0);
  }
}

// Round 7
// 1104.313 us; speedup vs baseline: 6.0164x; 1.0193x over previous
//
#include <hip/hip_runtime.h>

// R7: R6 + merged QKV projection GEMM (N=3*HC*E, range-switched epilogue:
// q/k straight, v transposed) and split-K out-projection with fp32 atomicAdd.
// Keeps: XCD swizzle, LDS dbuf BK=32, bf16 scores, wave-per-row softmax.

typedef short s8v __attribute__((ext_vector_type(8)));   // 8 bf16 = 4 VGPRs
typedef float f4v __attribute__((ext_vector_type(4)));
typedef unsigned short us;
typedef us us4v __attribute__((ext_vector_type(4)));
typedef us us8v __attribute__((ext_vector_type(8)));

__device__ inline us f2b(float f) {  // fp32 -> bf16 RNE
  union { float f; unsigned u; } v; v.f = f;
  unsigned r = v.u + 0x7FFFu + ((v.u >> 16) & 1u);
  return (us)(r >> 16);
}
__device__ inline float b2f(us b) {
  union { unsigned u; float f; } v; v.u = ((unsigned)b) << 16;
  return v.f;
}

// async global->LDS, 16 B per lane; LDS dest = wave-uniform base + lane*16.
__device__ inline void gld16(const us* g, us* l) {
  __builtin_amdgcn_global_load_lds(
      (const __attribute__((address_space(1))) void*)g,
      (__attribute__((address_space(3))) void*)l, 16, 0, 0);
}

// NT GEMM core: C = alpha * A @ B^T, A[M,K] (lda), B[N,K] (ldb), bf16.
// z = (zo<<L)|zi -> operand offsets zo*s?0 + zi*s?1.
// EPI 1: bf16 out (+bias[gc], *alpha), slice zo*sC0+zi*sC1.
// EPI 3: merged QKV epilogue — section = col0>>sbits: 0->Cv (straight,+bias),
//        1->C2 (straight,+bias2), 2->C3 (transposed V^T,+bias3). z = batch.
// EPI 5: fp32 atomicAdd into Cv (split-K out-projection).
template <int EPI>
__global__ __launch_bounds__(256, 4) void gemm_nt(
    const us* __restrict__ A, int lda, long long sA0, long long sA1,
    const us* __restrict__ Bm, int ldb, long long sB0, long long sB1,
    const float* __restrict__ bias, const float* __restrict__ bias2,
    const float* __restrict__ bias3,
    void* __restrict__ Cv, void* __restrict__ C2, void* __restrict__ C3,
    int ldc, long long sC0, long long sC1,
    int K, float alpha, int L, int sbits) {
  __shared__ us As[2][4096];  // 128 rows x 32 k per buf, fragment-linear
  __shared__ us Bs[2][4096];
  const int t = threadIdx.x;
  const int wv = t >> 6, ln = t & 63;
  const int m16 = ln & 15, quad = ln >> 4;

  // XCD-aware swizzle: flat%8 -> XCD (dispatch heuristic). Remap so each XCD
  // owns a contiguous nid range -> operand slices stay L2-resident.
  const int gx = gridDim.x, gxy = gx * gridDim.y;
  const int nblk = gxy * gridDim.z;
  const int flat = blockIdx.x + gx * blockIdx.y + gxy * blockIdx.z;
  int nid = flat;
  if ((nblk & 7) == 0) nid = (flat & 7) * (nblk >> 3) + (flat >> 3);
  const int bz = nid / gxy, rem = nid % gxy;
  const int by = rem / gx, bx = rem % gx;

  const long long row0 = (long long)by * 128;
  const long long col0 = (long long)bx * 128;
  const int zo = bz >> L, zi = bz & ((1 << L) - 1);
  const us* Az = A + zo * sA0 + zi * sA1;
  const us* Bz = Bm + zo * sB0 + zi * sB1;

  // chunk c = mb*64 + qd*16 + mm -> row mb*16+mm, k = qd*8 (512 chunks/tile).
  int offA[2], offB[2];
#pragma unroll
  for (int j = 0; j < 2; ++j) {
    const int c = t + 256 * j;
    const int mb = c >> 6, qd = (c >> 4) & 3, mm = c & 15;
    offA[j] = (int)((row0 + mb * 16 + mm) * (long long)lda + qd * 8);
    offB[j] = (int)((col0 + mb * 16 + mm) * (long long)ldb + qd * 8);
  }

  f4v acc[4][4];
#pragma unroll
  for (int r = 0; r < 4; ++r)
#pragma unroll
    for (int c = 0; c < 4; ++c) acc[r][c] = (f4v){0.f, 0.f, 0.f, 0.f};

  const int nk = K >> 5;
  const int fo = quad * 16 + m16;

  // prologue: stage k-tile 0 into buffer 0
#pragma unroll
  for (int j = 0; j < 2; ++j) {
    gld16(Az + offA[j], (us*)As[0] + (256 * j + wv * 64) * 8);
    gld16(Bz + offB[j], (us*)Bs[0] + (256 * j + wv * 64) * 8);
  }

  for (int i = 0; i < nk; ++i) {
    __syncthreads();  // drains vmcnt: buf (i&1) staged; prev reads done
    const int cur = i & 1;
    if (i + 1 < nk) {  // prefetch next tile into alternate buffer
      const int kof = (i + 1) << 5;
#pragma unroll
      for (int j = 0; j < 2; ++j) {
        gld16(Az + offA[j] + kof, (us*)As[cur ^ 1] + (256 * j + wv * 64) * 8);
        gld16(Bz + offB[j] + kof, (us*)Bs[cur ^ 1] + (256 * j + wv * 64) * 8);
      }
    }
    s8v af[4], bf[4];
#pragma unroll
    for (int r = 0; r < 4; ++r)
      af[r] = *(const s8v*)&As[cur][(((wv & 1) * 4 + r) * 64 + fo) * 8];
#pragma unroll
    for (int c = 0; c < 4; ++c)
      bf[c] = *(const s8v*)&Bs[cur][(((wv >> 1) * 4 + c) * 64 + fo) * 8];
#pragma unroll
    for (int r = 0; r < 4; ++r)
#pragma unroll
      for (int c = 0; c < 4; ++c)
        acc[r][c] = __builtin_amdgcn_mfma_f32_16x16x32_bf16(af[r], bf[c], acc[r][c], 0, 0, 0);
  }

  // Epilogue. C/D layout: col = lane&15, row = quad*4 + reg (m89-verified).
#pragma unroll
  for (int r = 0; r < 4; ++r) {
    const long long gr0 = row0 + (wv & 1) * 64 + r * 16 + quad * 4;
#pragma unroll
    for (int c = 0; c < 4; ++c) {
      const long long gc = col0 + (wv >> 1) * 64 + c * 16 + m16;
      if (EPI == 1) {
        us* C = (us*)Cv + zo * sC0 + zi * sC1;
        const float bb = bias ? bias[gc] : 0.f;
#pragma unroll
        for (int g = 0; g < 4; ++g)
          C[(gr0 + g) * (long long)ldc + gc] = f2b(acc[r][c][g] * alpha + bb);
      } else if (EPI == 3) {
        // sections of HC*512 cols each: 0=q, 1=k, 2=v(transposed)
        const int which = (int)(col0 >> sbits);
        const int gsec = (int)gc & ((1 << sbits) - 1);
        const int hc = gsec >> 9, e = (int)gc & 511;
        const long long slice =
            ((long long)zo * (1 << (sbits - 9)) + hc) * 1048576LL;  // S*E
        if (which == 0) {
          us* C = (us*)Cv;
          const float bb = bias[gsec];
#pragma unroll
          for (int g = 0; g < 4; ++g)
            C[slice + (gr0 + g) * 512 + e] = f2b(acc[r][c][g] + bb);
        } else if (which == 1) {
          us* C = (us*)C2;
          const float bb = bias2[gsec];
#pragma unroll
          for (int g = 0; g < 4; ++g)
            C[slice + (gr0 + g) * 512 + e] = f2b(acc[r][c][g] + bb);
        } else {
          us* C = (us*)C3;
          const float bb = bias3[gsec];
          us4v pk;
#pragma unroll
          for (int g = 0; g < 4; ++g) pk[g] = f2b(acc[r][c][g] + bb);
          *(us4v*)&C[slice + (long long)e * 2048 + gr0] = pk;  // e*S + s
        }
      } else {  // EPI 5: split-K atomic accumulate (fp32)
        float* C = (float*)Cv + zo * sC0;
        float* p = C + gr0 * ldc + gc;
#pragma unroll
        for (int g = 0; g < 4; ++g)
          atomicAdd(&p[(long long)g * ldc], acc[r][c][g] * alpha);
      }
    }
  }
}

// In-place row softmax on bf16, 2048 cols. One wave per row, 4 rows/block,
// shuffle-only reduction (no LDS, no barriers).
__global__ __launch_bounds__(256) void softmax_bf16(us* __restrict__ sc) {
  const int w = threadIdx.x >> 6, ln = threadIdx.x & 63;
  us* p = sc + ((long long)blockIdx.y * 2048 + (long long)(blockIdx.x * 4 + w)) * 2048;
  us8v raw[4];
  float vals[32];
#pragma unroll
  for (int j = 0; j < 4; ++j) raw[j] = *(const us8v*)(p + j * 512 + ln * 8);
  float m = -1e30f;
#pragma unroll
  for (int j = 0; j < 4; ++j)
#pragma unroll
    for (int u = 0; u < 8; ++u) {
      vals[j * 8 + u] = b2f(raw[j][u]);
      m = fmaxf(m, vals[j * 8 + u]);
    }
#pragma unroll
  for (int off = 32; off; off >>= 1) m = fmaxf(m, __shfl_xor(m, off, 64));
  float s = 0.f;
#pragma unroll
  for (int u = 0; u < 32; ++u) {
    vals[u] = __expf(vals[u] - m);
    s += vals[u];
  }
#pragma unroll
  for (int off = 32; off; off >>= 1) s += __shfl_xor(s, off, 64);
  const float inv = 1.f / s;
#pragma unroll
  for (int j = 0; j < 4; ++j) {
    us8v o;
#pragma unroll
    for (int u = 0; u < 8; ++u) o[u] = f2b(vals[j * 8 + u] * inv);
    *(us8v*)(p + j * 512 + ln * 8) = o;
  }
}

__global__ __launch_bounds__(256) void conv_bf16(const float* __restrict__ in,
                                                 us* __restrict__ out, int n4) {
  const int i = blockIdx.x * 256 + threadIdx.x;
  if (i < n4) {
    const float4 f = ((const float4*)in)[i];
    us4v o;
    o[0] = f2b(f.x); o[1] = f2b(f.y); o[2] = f2b(f.z); o[3] = f2b(f.w);
    ((us4v*)out)[i] = o;
  }
}

// in [Z][R][C] fp32 -> bf16 transposed [C][R], z-routed:
// dst = out + (z>>Lc)*sChunk + (z&mask)*(R*C)
__global__ __launch_bounds__(256) void conv_transpose(const float* __restrict__ in,
                                                      us* __restrict__ out,
                                                      int R, int C, int Lc,
                                                      int mask, long long sChunk) {
  __shared__ float tile[32][33];
  const int tx = threadIdx.x & 31, ty = threadIdx.x >> 5;
  const int z = blockIdx.z;
  const long long zi = (long long)z * R * C;
  us* dst = out + (long long)(z >> Lc) * sChunk + (long long)(z & mask) * R * C;
  const int r0 = blockIdx.y * 32, c0 = blockIdx.x * 32;
#pragma unroll
  for (int j = 0; j < 4; ++j)
    tile[ty + 8 * j][tx] = in[zi + (long long)(r0 + ty + 8 * j) * C + c0 + tx];
  __syncthreads();
#pragma unroll
  for (int j = 0; j < 4; ++j)
    dst[(long long)(c0 + ty + 8 * j) * R + r0 + tx] = f2b(tile[tx][ty + 8 * j]);
}

__global__ __launch_bounds__(256) void init_out_kernel(float* __restrict__ out,
                                                       const float* __restrict__ bp,
                                                       int total) {
  const int i = blockIdx.x * 256 + threadIdx.x;
  if (i < total) out[i] = bp[i & 511];  // D=512
}

extern "C" void kernel_launch(void* const* d_in, const int* in_sizes, int n_in,
                              void* d_out, int out_size, void* d_ws, size_t ws_size,
                              hipStream_t stream) {
  constexpr int Bb = 4, S = 2048, D = 512, H = 8, E = 512, HE = 4096;
  const float* x  = (const float*)d_in[0];
  const float* Wq = (const float*)d_in[1];
  const float* bq = (const float*)d_in[2];
  const float* Wk = (const float*)d_in[3];
  const float* bk = (const float*)d_in[4];
  const float* Wv = (const float*)d_in[5];
  const float* bv = (const float*)d_in[6];
  const float* Wp = (const float*)d_in[7];
  const float* bp = (const float*)d_in[8];
  float* out = (float*)d_out;

  const long long SE = (long long)S * E, SS = (long long)S * S;
  const long long SD = (long long)S * D, ED = (long long)E * D;

  // Fixed region: xh + packed QKV weights W3 + WpT (25.2 MB).
  us* xh  = (us*)d_ws;            // B*S*D          4,194,304
  us* W3  = xh + 4194304;         // [chunk][3][HC*E][D]  6,291,456 total
  us* WpT = W3 + 6291456;         // [D][HE]        2,097,152
  us* dyn = WpT + 2097152;

  // Head-chunk size. oh aliases qh (dead after scores GEMM).
  const size_t fixedB = (size_t)(4194304 + 6291456 + 2097152) * 2;
  int HC = 8;
  while (HC > 1) {
    const size_t need = fixedB + (size_t)HC * (3 * (size_t)Bb * SE + (size_t)Bb * SS) * 2;
    if (need <= ws_size) break;
    HC >>= 1;
  }
  const int Lh = (HC == 8) ? 3 : (HC == 4) ? 2 : (HC == 2) ? 1 : 0;
  const int BHC = Bb * HC;
  const int sbits = 9 + Lh;  // section size HC*512 cols

  us* qh = dyn;                       // [b*HC+hc][S][E]
  us* kh = qh + (size_t)BHC * SE;
  us* vT = kh + (size_t)BHC * SE;     // [b*HC+hc][E][S]
  us* sc = vT + (size_t)BHC * SE;     // [b*HC+hc][S][S]
  us* oh = qh;                        // alias: [b][S][HC][E]

  const dim3 tb(256);
  init_out_kernel<<<dim3((Bb * S * D + 255) / 256), tb, 0, stream>>>(out, bp, Bb * S * D);
  conv_bf16<<<dim3(4194304 / 4 / 256), tb, 0, stream>>>(x, xh, 4194304 / 4);
  const long long sChunk = 3LL * HC * ED;  // per-chunk W3 stride
  conv_transpose<<<dim3(16, 16, H), tb, 0, stream>>>(Wq, W3, D, E, Lh, HC - 1, sChunk);
  conv_transpose<<<dim3(16, 16, H), tb, 0, stream>>>(Wk, W3 + HC * ED, D, E, Lh, HC - 1, sChunk);
  conv_transpose<<<dim3(16, 16, H), tb, 0, stream>>>(Wv, W3 + 2 * HC * ED, D, E, Lh, HC - 1, sChunk);
  conv_transpose<<<dim3(16, 128, 1), tb, 0, stream>>>(Wp, WpT, HE, D, 0, 0, 0);

  const float aS = 0.044194173824159216f;  // 1/sqrt(512)
  const dim3 gQKV(3 * HC * E / 128, 16, Bb);   // e.g. 48 x 16 x 4 (HC=4)
  const dim3 gS(16, 16, BHC);
  const dim3 gPV(4, 16, BHC);
  const dim3 gOP(4, 16, BHC);                  // split-K: z = (b, j)

  for (int c = 0; c < H / HC; ++c) {
    const int h0 = c * HC;
    // Merged QKV projection: [S,D] @ [3*HC*E, D]^T; epilogue routes sections.
    gemm_nt<3><<<gQKV, tb, 0, stream>>>(
        xh, D, SD, 0, W3 + c * sChunk, D, 0, 0,
        bq + h0 * E, bk + h0 * E, bv + h0 * E,
        qh, kh, vT, 512, 0, SE, D, 1.f, 0, sbits);
    // scores = (Q K^T)/sqrt(E) -> bf16 [z][S][S]
    gemm_nt<1><<<gS, tb, 0, stream>>>(
        qh, E, (long long)HC * SE, SE, kh, E, (long long)HC * SE, SE,
        nullptr, nullptr, nullptr, sc, nullptr, nullptr,
        S, (long long)HC * SS, SS, E, aS, Lh, 0);
    softmax_bf16<<<dim3(S / 4, BHC), tb, 0, stream>>>(sc);
    // O = P @ V (B = V^T [E][S]) -> oh [b][S][HC][E]
    gemm_nt<1><<<gPV, tb, 0, stream>>>(
        sc, S, (long long)HC * SS, SS, vT, S, (long long)HC * SE, SE,
        nullptr, nullptr, nullptr, oh, nullptr, nullptr,
        HC * E, (long long)S * HC * E, E, S, 1.f, Lh, 0);
    // out += O @ Wp-chunk, split-K: z=(b, j), K=512 per split, atomicAdd.
    gemm_nt<5><<<gOP, tb, 0, stream>>>(
        oh, HC * E, (long long)S * HC * E, 512,
        WpT + (long long)h0 * E, HE, 0, 512,
        nullptr, nullptr, nullptr, out, nullptr, nullptr,
        D, SD, 0, 512, 1.f, Lh, 0);
  }
}

// Round 8
// 950.975 us; speedup vs baseline: 6.9865x; 1.1612x over previous
//
#include <hip/hip_runtime.h>

// R8: 256x128 block tile / 8 waves (2x MFMA per barrier, 16 waves/CU) and
// softmax fused away: scores epilogue writes P' = exp(alpha*s - 4) bf16 and
// atomicAdds row sums l[]; PV epilogue scales by 1/l. Keeps XCD swizzle,
// LDS dbuf BK=32, merged QKV, split-K out-proj.

typedef short s8v __attribute__((ext_vector_type(8)));   // 8 bf16 = 4 VGPRs
typedef float f4v __attribute__((ext_vector_type(4)));
typedef unsigned short us;
typedef us us4v __attribute__((ext_vector_type(4)));

__device__ inline us f2b(float f) {  // fp32 -> bf16 RNE
  union { float f; unsigned u; } v; v.f = f;
  unsigned r = v.u + 0x7FFFu + ((v.u >> 16) & 1u);
  return (us)(r >> 16);
}

// async global->LDS, 16 B per lane; LDS dest = wave-uniform base + lane*16.
__device__ inline void gld16(const us* g, us* l) {
  __builtin_amdgcn_global_load_lds(
      (const __attribute__((address_space(1))) void*)g,
      (__attribute__((address_space(3))) void*)l, 16, 0, 0);
}

// NT GEMM core: 256(M) x 128(N) tile, 8 waves; A[M,K] (lda), B[N,K] (ldb).
// z = (zo<<L)|zi -> operand offsets zo*s?0 + zi*s?1.
// EPI 3: merged QKV epilogue (sections q/k straight+bias, v transposed+bias).
// EPI 5: fp32 atomicAdd into Cv (split-K out-projection).
// EPI 6: scores: P' = bf16(exp(alpha*s - 4)) to Cv; row-sums atomicAdd to C2.
// EPI 7: PV: bf16(acc / l[row]) to Cv; l read from C2.
template <int EPI>
__global__ __launch_bounds__(512, 4) void gemm_nt(
    const us* __restrict__ A, int lda, long long sA0, long long sA1,
    const us* __restrict__ Bm, int ldb, long long sB0, long long sB1,
    const float* __restrict__ bias, const float* __restrict__ bias2,
    const float* __restrict__ bias3,
    void* __restrict__ Cv, void* __restrict__ C2, void* __restrict__ C3,
    int ldc, long long sC0, long long sC1,
    int K, float alpha, int L, int sbits) {
  __shared__ us As[2][8192];  // 256 x 32 per buf, fragment-linear (1024 chunks)
  __shared__ us Bs[2][4096];  // 128 x 32 per buf (512 chunks)
  const int t = threadIdx.x;
  const int wv = t >> 6, ln = t & 63;
  const int m16 = ln & 15, quad = ln >> 4;

  // XCD-aware swizzle: flat%8 -> XCD. Remap so each XCD owns a contiguous
  // nid range -> operand slices stay L2-resident.
  const int gx = gridDim.x, gxy = gx * gridDim.y;
  const int nblk = gxy * gridDim.z;
  const int flat = blockIdx.x + gx * blockIdx.y + gxy * blockIdx.z;
  int nid = flat;
  if ((nblk & 7) == 0) nid = (flat & 7) * (nblk >> 3) + (flat >> 3);
  const int bz = nid / gxy, rem = nid % gxy;
  const int by = rem / gx, bx = rem % gx;

  const long long row0 = (long long)by * 256;
  const long long col0 = (long long)bx * 128;
  const int zo = bz >> L, zi = bz & ((1 << L) - 1);
  const us* Az = A + zo * sA0 + zi * sA1;
  const us* Bz = Bm + zo * sB0 + zi * sB1;

  // chunk c = mb*64 + qd*16 + mm -> row mb*16+mm, k = qd*8.
  // A: 1024 chunks -> thread t stages c = t, t+512. B: 512 chunks -> c = t.
  int offA[2], offB;
#pragma unroll
  for (int j = 0; j < 2; ++j) {
    const int c = t + 512 * j;
    const int mb = c >> 6, qd = (c >> 4) & 3, mm = c & 15;
    offA[j] = (int)((row0 + mb * 16 + mm) * (long long)lda + qd * 8);
  }
  {
    const int mb = t >> 6, qd = (t >> 4) & 3, mm = t & 15;
    offB = (int)((col0 + mb * 16 + mm) * (long long)ldb + qd * 8);
  }

  f4v acc[4][4];
#pragma unroll
  for (int r = 0; r < 4; ++r)
#pragma unroll
    for (int c = 0; c < 4; ++c) acc[r][c] = (f4v){0.f, 0.f, 0.f, 0.f};

  const int nk = K >> 5;
  const int fo = quad * 16 + m16;
  const int arow = wv & 3, bcol = wv >> 2;  // wave -> 64-row / 64-col group

  // prologue: stage k-tile 0 into buffer 0
#pragma unroll
  for (int j = 0; j < 2; ++j)
    gld16(Az + offA[j], (us*)As[0] + (512 * j + wv * 64) * 8);
  gld16(Bz + offB, (us*)Bs[0] + (wv * 64) * 8);

  for (int i = 0; i < nk; ++i) {
    __syncthreads();  // drains vmcnt: buf (i&1) staged; prev reads done
    const int cur = i & 1;
    if (i + 1 < nk) {  // prefetch next tile into alternate buffer
      const int kof = (i + 1) << 5;
#pragma unroll
      for (int j = 0; j < 2; ++j)
        gld16(Az + offA[j] + kof, (us*)As[cur ^ 1] + (512 * j + wv * 64) * 8);
      gld16(Bz + offB + kof, (us*)Bs[cur ^ 1] + (wv * 64) * 8);
    }
    s8v af[4], bf[4];
#pragma unroll
    for (int r = 0; r < 4; ++r)
      af[r] = *(const s8v*)&As[cur][((arow * 4 + r) * 64 + fo) * 8];
#pragma unroll
    for (int c = 0; c < 4; ++c)
      bf[c] = *(const s8v*)&Bs[cur][((bcol * 4 + c) * 64 + fo) * 8];
#pragma unroll
    for (int r = 0; r < 4; ++r)
#pragma unroll
      for (int c = 0; c < 4; ++c)
        acc[r][c] = __builtin_amdgcn_mfma_f32_16x16x32_bf16(af[r], bf[c], acc[r][c], 0, 0, 0);
  }

  // Epilogue. C/D layout: col = lane&15, row = quad*4 + reg (m89-verified).
  if (EPI == 6) {  // P' = exp(alpha*s - 4), then row-sum partials
#pragma unroll
    for (int r = 0; r < 4; ++r)
#pragma unroll
      for (int c = 0; c < 4; ++c)
#pragma unroll
        for (int g = 0; g < 4; ++g)
          acc[r][c][g] = __expf(fmaf(acc[r][c][g], alpha, -4.f));
  }
#pragma unroll
  for (int r = 0; r < 4; ++r) {
    const int inRow = arow * 64 + r * 16 + quad * 4;
    const long long gr0 = row0 + inRow;
#pragma unroll
    for (int c = 0; c < 4; ++c) {
      const long long gc = col0 + bcol * 64 + c * 16 + m16;
      if (EPI == 3) {
        // sections of HC*512 cols each: 0=q, 1=k, 2=v(transposed)
        const int which = (int)(gc >> sbits);
        const int gsec = (int)gc & ((1 << sbits) - 1);
        const int hc = gsec >> 9, e = (int)gc & 511;
        const long long slice =
            ((long long)zo * (1 << (sbits - 9)) + hc) * 1048576LL;  // S*E
        if (which == 0) {
          us* C = (us*)Cv;
          const float bb = bias[gsec];
#pragma unroll
          for (int g = 0; g < 4; ++g)
            C[slice + (gr0 + g) * 512 + e] = f2b(acc[r][c][g] + bb);
        } else if (which == 1) {
          us* C = (us*)C2;
          const float bb = bias2[gsec];
#pragma unroll
          for (int g = 0; g < 4; ++g)
            C[slice + (gr0 + g) * 512 + e] = f2b(acc[r][c][g] + bb);
        } else {
          us* C = (us*)C3;
          const float bb = bias3[gsec];
          us4v pk;
#pragma unroll
          for (int g = 0; g < 4; ++g) pk[g] = f2b(acc[r][c][g] + bb);
          *(us4v*)&C[slice + (long long)e * 2048 + gr0] = pk;  // e*S + s
        }
      } else if (EPI == 5) {  // split-K atomic accumulate (fp32)
        float* C = (float*)Cv + zo * sC0;
        float* p = C + gr0 * ldc + gc;
#pragma unroll
        for (int g = 0; g < 4; ++g)
          atomicAdd(&p[(long long)g * ldc], acc[r][c][g] * alpha);
      } else if (EPI == 6) {  // store P' bf16
        us* C = (us*)Cv + zo * sC0 + zi * sC1;
#pragma unroll
        for (int g = 0; g < 4; ++g)
          C[(gr0 + g) * (long long)ldc + gc] = f2b(acc[r][c][g]);
      } else {  // EPI 7: PV, scale by 1/l[row]
        us* C = (us*)Cv + zo * sC0 + zi * sC1;
        const float* lrow = (const float*)C2 + (long long)bz * 2048;
#pragma unroll
        for (int g = 0; g < 4; ++g) {
          const float inv = 1.f / lrow[gr0 + g];
          C[(gr0 + g) * (long long)ldc + gc] = f2b(acc[r][c][g] * inv);
        }
      }
    }
    if (EPI == 6) {  // row-sum partials over this wave's 64 cols
      float* lsum = (float*)C2 + (long long)bz * 2048;
#pragma unroll
      for (int g = 0; g < 4; ++g) {
        float s = acc[r][0][g] + acc[r][1][g] + acc[r][2][g] + acc[r][3][g];
        s += __shfl_xor(s, 1, 64);
        s += __shfl_xor(s, 2, 64);
        s += __shfl_xor(s, 4, 64);
        s += __shfl_xor(s, 8, 64);
        if (m16 == 0) atomicAdd(&lsum[gr0 + g], s);
      }
    }
  }
}

__global__ __launch_bounds__(256) void conv_bf16(const float* __restrict__ in,
                                                 us* __restrict__ out, int n4) {
  const int i = blockIdx.x * 256 + threadIdx.x;
  if (i < n4) {
    const float4 f = ((const float4*)in)[i];
    us4v o;
    o[0] = f2b(f.x); o[1] = f2b(f.y); o[2] = f2b(f.z); o[3] = f2b(f.w);
    ((us4v*)out)[i] = o;
  }
}

// in [Z][R][C] fp32 -> bf16 transposed [C][R], z-routed:
// dst = out + (z>>Lc)*sChunk + (z&mask)*(R*C)
__global__ __launch_bounds__(256) void conv_transpose(const float* __restrict__ in,
                                                      us* __restrict__ out,
                                                      int R, int C, int Lc,
                                                      int mask, long long sChunk) {
  __shared__ float tile[32][33];
  const int tx = threadIdx.x & 31, ty = threadIdx.x >> 5;
  const int z = blockIdx.z;
  const long long zi = (long long)z * R * C;
  us* dst = out + (long long)(z >> Lc) * sChunk + (long long)(z & mask) * R * C;
  const int r0 = blockIdx.y * 32, c0 = blockIdx.x * 32;
#pragma unroll
  for (int j = 0; j < 4; ++j)
    tile[ty + 8 * j][tx] = in[zi + (long long)(r0 + ty + 8 * j) * C + c0 + tx];
  __syncthreads();
#pragma unroll
  for (int j = 0; j < 4; ++j)
    dst[(long long)(c0 + ty + 8 * j) * R + r0 + tx] = f2b(tile[tx][ty + 8 * j]);
}

// out[b,s,:] = bp[:]; also zeroes the l (row-sum) region.
__global__ __launch_bounds__(256) void init_out_kernel(float* __restrict__ out,
                                                       const float* __restrict__ bp,
                                                       int total,
                                                       float* __restrict__ lz,
                                                       int lcnt) {
  const int i = blockIdx.x * 256 + threadIdx.x;
  if (i < total) out[i] = bp[i & 511];  // D=512
  else if (i < total + lcnt) lz[i - total] = 0.f;
}

extern "C" void kernel_launch(void* const* d_in, const int* in_sizes, int n_in,
                              void* d_out, int out_size, void* d_ws, size_t ws_size,
                              hipStream_t stream) {
  constexpr int Bb = 4, S = 2048, D = 512, H = 8, E = 512, HE = 4096;
  const float* x  = (const float*)d_in[0];
  const float* Wq = (const float*)d_in[1];
  const float* bq = (const float*)d_in[2];
  const float* Wk = (const float*)d_in[3];
  const float* bk = (const float*)d_in[4];
  const float* Wv = (const float*)d_in[5];
  const float* bv = (const float*)d_in[6];
  const float* Wp = (const float*)d_in[7];
  const float* bp = (const float*)d_in[8];
  float* out = (float*)d_out;

  const long long SE = (long long)S * E, SS = (long long)S * S;
  const long long SD = (long long)S * D, ED = (long long)E * D;

  // Fixed region: xh + packed QKV weights W3 + WpT (25.2 MB).
  us* xh  = (us*)d_ws;            // B*S*D          4,194,304
  us* W3  = xh + 4194304;         // [chunk][3][HC*E][D]  6,291,456 total
  us* WpT = W3 + 6291456;         // [D][HE]        2,097,152
  us* dyn = WpT + 2097152;

  // Head-chunk size. oh aliases qh (dead after scores GEMM).
  const size_t fixedB = (size_t)(4194304 + 6291456 + 2097152) * 2;
  const size_t lB = (size_t)H * Bb * S * 4;  // all chunks' row-sum buffers
  int HC = 8;
  while (HC > 1) {
    const size_t need = fixedB + lB +
        (size_t)HC * (3 * (size_t)Bb * SE + (size_t)Bb * SS) * 2;
    if (need <= ws_size) break;
    HC >>= 1;
  }
  const int Lh = (HC == 8) ? 3 : (HC == 4) ? 2 : (HC == 2) ? 1 : 0;
  const int BHC = Bb * HC;
  const int sbits = 9 + Lh;  // QKV section size = HC*512 cols

  us* qh = dyn;                       // [b*HC+hc][S][E]
  us* kh = qh + (size_t)BHC * SE;
  us* vT = kh + (size_t)BHC * SE;     // [b*HC+hc][E][S]
  us* sc = vT + (size_t)BHC * SE;     // [b*HC+hc][S][S]  (P' = exp(as-4))
  float* lb = (float*)(sc + (size_t)BHC * SS);  // [H*Bb][S] row sums
  us* oh = qh;                        // alias: [b][S][HC][E]

  const dim3 tb(256), tg(512);
  const int lcnt = H * Bb * S;
  init_out_kernel<<<dim3((Bb * S * D + lcnt + 255) / 256), tb, 0, stream>>>(
      out, bp, Bb * S * D, lb, lcnt);
  conv_bf16<<<dim3(4194304 / 4 / 256), tb, 0, stream>>>(x, xh, 4194304 / 4);
  const long long sChunk = 3LL * HC * ED;  // per-chunk W3 stride
  conv_transpose<<<dim3(16, 16, H), tb, 0, stream>>>(Wq, W3, D, E, Lh, HC - 1, sChunk);
  conv_transpose<<<dim3(16, 16, H), tb, 0, stream>>>(Wk, W3 + HC * ED, D, E, Lh, HC - 1, sChunk);
  conv_transpose<<<dim3(16, 16, H), tb, 0, stream>>>(Wv, W3 + 2 * HC * ED, D, E, Lh, HC - 1, sChunk);
  conv_transpose<<<dim3(16, 128, 1), tb, 0, stream>>>(Wp, WpT, HE, D, 0, 0, 0);

  const float aS = 0.044194173824159216f;  // 1/sqrt(512)
  const dim3 gQKV(3 * HC * E / 128, 8, Bb);    // 256-row tiles: S/256 = 8
  const dim3 gS(16, 8, BHC);
  const dim3 gPV(4, 8, BHC);
  const dim3 gOP(4, 8, BHC);                   // split-K: z = (b, j)

  for (int c = 0; c < H / HC; ++c) {
    const int h0 = c * HC;
    float* lc = lb + (long long)c * BHC * S;
    // Merged QKV projection: [S,D] @ [3*HC*E, D]^T; epilogue routes sections.
    gemm_nt<3><<<gQKV, tg, 0, stream>>>(
        xh, D, SD, 0, W3 + c * sChunk, D, 0, 0,
        bq + h0 * E, bk + h0 * E, bv + h0 * E,
        qh, kh, vT, 512, 0, SE, D, 1.f, 0, sbits);
    // P' = exp((Q K^T)/sqrt(E) - 4) -> bf16 [z][S][S]; row sums -> lc
    gemm_nt<6><<<gS, tg, 0, stream>>>(
        qh, E, (long long)HC * SE, SE, kh, E, (long long)HC * SE, SE,
        nullptr, nullptr, nullptr, sc, lc, nullptr,
        S, (long long)HC * SS, SS, E, aS, Lh, 0);
    // O = (P' @ V) / l  -> oh [b][S][HC][E]
    gemm_nt<7><<<gPV, tg, 0, stream>>>(
        sc, S, (long long)HC * SS, SS, vT, S, (long long)HC * SE, SE,
        nullptr, nullptr, nullptr, oh, lc, nullptr,
        HC * E, (long long)S * HC * E, E, S, 1.f, Lh, 0);
    // out += O @ Wp-chunk, split-K: z=(b, j), K=512 per split, atomicAdd.
    gemm_nt<5><<<gOP, tg, 0, stream>>>(
        oh, HC * E, (long long)S * HC * E, 512,
        WpT + (long long)h0 * E, HE, 0, 512,
        nullptr, nullptr, nullptr, out, nullptr, nullptr,
        D, SD, 0, 512, 1.f, Lh, 0);
  }
}